// Round 5
// baseline (520.019 us; speedup 1.0000x reference)
//
#include <hip/hip_runtime.h>

#define NN 10000      // nodes
#define NE 320000     // edges
#define NH 128        // hidden
#define C0N 10
#define C1N 5

// ---------------------------------------------------------------- graph prep
__global__ void k_deg_cnt(const int* __restrict__ ei, const float* __restrict__ ew,
                          float* deg, int* cnt) {
  int e = blockIdx.x * 256 + threadIdx.x;
  if (e >= NE) return;
  int c = ei[NE + e];
  atomicAdd(&deg[c], ew[e]);
  atomicAdd(&cnt[c], 1);
}

__global__ __launch_bounds__(1024) void k_scan(const int* __restrict__ cnt, int* __restrict__ rowptr) {
  __shared__ int part[1024];
  int t = threadIdx.x;
  const int chunk = (NN + 1023) / 1024;   // 10
  int base = t * chunk;
  int s = 0;
  for (int i = 0; i < chunk; i++) { int idx = base + i; if (idx < NN) s += cnt[idx]; }
  part[t] = s; __syncthreads();
  for (int off = 1; off < 1024; off <<= 1) {
    int v = (t >= off) ? part[t - off] : 0;
    __syncthreads();
    part[t] += v;
    __syncthreads();
  }
  int run = (t == 0) ? 0 : part[t - 1];
  for (int i = 0; i < chunk; i++) { int idx = base + i; if (idx < NN) { rowptr[idx] = run; run += cnt[idx]; } }
  if (t == 1023) rowptr[NN] = run;   // tail threads sum 0 past NN, so this == NE
}

__global__ void k_fill(const int* __restrict__ ei, const float* __restrict__ ew,
                       const float* __restrict__ deg, const int* __restrict__ rowptr,
                       int* __restrict__ fill, int* __restrict__ csrs, float* __restrict__ csrw) {
  int e = blockIdx.x * 256 + threadIdx.x;
  if (e >= NE) return;
  int r = ei[e], c = ei[NE + e];
  float nrm = rsqrtf(deg[r] + 1.0f) * ew[e] * rsqrtf(deg[c] + 1.0f);
  int pos = rowptr[c] + atomicAdd(&fill[c], 1);
  csrs[pos] = r;
  csrw[pos] = nrm;
}

// ---------------------------------------------------------------- GEMM (fp32, 32x64 tile, 256 thr)
// 626 blocks for M=10000 -> 2-3 blocks/CU co-resident (barrier-stall hiding).
template<int BIAS, int RELU>
__global__ __launch_bounds__(256) void gemm_k(
    const float* __restrict__ A, int lda,
    const float* __restrict__ B, int ldb,
    const float* __restrict__ bias,
    float* __restrict__ C, int ldc,
    int M, int K) {
  __shared__ __align__(16) float As[16][36];
  __shared__ __align__(16) float Bs[16][68];
  int bm = blockIdx.x * 32, bn = blockIdx.y * 64;
  int t = threadIdx.x;
  int tx = t & 15, ty = t >> 4;
  float acc[2][4];
  #pragma unroll
  for (int i = 0; i < 2; i++)
    #pragma unroll
    for (int j = 0; j < 4; j++) acc[i][j] = 0.f;

  for (int k0 = 0; k0 < K; k0 += 16) {
    if (t < 128) {
      int la_r = t >> 2, la_k = (t & 3) * 4;
      int ar = bm + la_r;
      float4 av = make_float4(0.f, 0.f, 0.f, 0.f);
      if (ar < M) av = *reinterpret_cast<const float4*>(&A[(size_t)ar * lda + k0 + la_k]);
      As[la_k + 0][la_r] = av.x; As[la_k + 1][la_r] = av.y;
      As[la_k + 2][la_r] = av.z; As[la_k + 3][la_r] = av.w;
    }
    {
      int lb_k = t >> 4, lb_n = (t & 15) * 4;
      *reinterpret_cast<float4*>(&Bs[lb_k][lb_n]) =
          *reinterpret_cast<const float4*>(&B[(size_t)(k0 + lb_k) * ldb + bn + lb_n]);
    }
    __syncthreads();
    #pragma unroll
    for (int k = 0; k < 16; k++) {
      float2 af = *reinterpret_cast<const float2*>(&As[k][ty * 2]);
      float4 bf = *reinterpret_cast<const float4*>(&Bs[k][tx * 4]);
      acc[0][0] = fmaf(af.x, bf.x, acc[0][0]); acc[0][1] = fmaf(af.x, bf.y, acc[0][1]);
      acc[0][2] = fmaf(af.x, bf.z, acc[0][2]); acc[0][3] = fmaf(af.x, bf.w, acc[0][3]);
      acc[1][0] = fmaf(af.y, bf.x, acc[1][0]); acc[1][1] = fmaf(af.y, bf.y, acc[1][1]);
      acc[1][2] = fmaf(af.y, bf.z, acc[1][2]); acc[1][3] = fmaf(af.y, bf.w, acc[1][3]);
    }
    __syncthreads();
  }
  int cb = bn + tx * 4;
  float4 bias4 = make_float4(0.f, 0.f, 0.f, 0.f);
  if (BIAS) bias4 = *reinterpret_cast<const float4*>(&bias[cb]);
  #pragma unroll
  for (int i = 0; i < 2; i++) {
    int r = bm + ty * 2 + i;
    if (r >= M) continue;
    float4 v = make_float4(acc[i][0], acc[i][1], acc[i][2], acc[i][3]);
    if (BIAS) { v.x += bias4.x; v.y += bias4.y; v.z += bias4.z; v.w += bias4.w; }
    if (RELU) {
      v.x = fmaxf(v.x, 0.f); v.y = fmaxf(v.y, 0.f);
      v.z = fmaxf(v.z, 0.f); v.w = fmaxf(v.w, 0.f);
    }
    *reinterpret_cast<float4*>(&C[(size_t)r * ldc + cb]) = v;
  }
}

// C = bn(A) @ B. BN affine derived from raw sums: m=s/NN, var=ss/NN-m^2.
__global__ __launch_bounds__(256) void gemm_bn(
    const float* __restrict__ A,
    const float* __restrict__ sums,     // [256] sum | sumsq
    const float* __restrict__ g, const float* __restrict__ b,
    const float* __restrict__ B,
    float* __restrict__ C, int M) {
  __shared__ __align__(16) float As[16][36];
  __shared__ __align__(16) float Bs[16][68];
  int bm = blockIdx.x * 32, bn = blockIdx.y * 64;
  int t = threadIdx.x;
  int tx = t & 15, ty = t >> 4;
  float acc[2][4];
  #pragma unroll
  for (int i = 0; i < 2; i++)
    #pragma unroll
    for (int j = 0; j < 4; j++) acc[i][j] = 0.f;

  const float invn = 1.0f / NN;
  for (int k0 = 0; k0 < NH; k0 += 16) {
    if (t < 128) {
      int la_r = t >> 2, la_k = (t & 3) * 4;
      int ar = bm + la_r;
      int cb = k0 + la_k;
      float4 av = make_float4(0.f, 0.f, 0.f, 0.f);
      if (ar < M) {
        float4 raw = *reinterpret_cast<const float4*>(&A[(size_t)ar * NH + cb]);
        float4 sm = *reinterpret_cast<const float4*>(&sums[cb]);
        float4 sq = *reinterpret_cast<const float4*>(&sums[NH + cb]);
        float4 gv = *reinterpret_cast<const float4*>(&g[cb]);
        float4 bv = *reinterpret_cast<const float4*>(&b[cb]);
        float m0 = sm.x * invn, m1 = sm.y * invn, m2 = sm.z * invn, m3 = sm.w * invn;
        av.x = (raw.x - m0) * (gv.x * rsqrtf(sq.x * invn - m0 * m0 + 1e-5f)) + bv.x;
        av.y = (raw.y - m1) * (gv.y * rsqrtf(sq.y * invn - m1 * m1 + 1e-5f)) + bv.y;
        av.z = (raw.z - m2) * (gv.z * rsqrtf(sq.z * invn - m2 * m2 + 1e-5f)) + bv.z;
        av.w = (raw.w - m3) * (gv.w * rsqrtf(sq.w * invn - m3 * m3 + 1e-5f)) + bv.w;
      }
      As[la_k + 0][la_r] = av.x; As[la_k + 1][la_r] = av.y;
      As[la_k + 2][la_r] = av.z; As[la_k + 3][la_r] = av.w;
    }
    {
      int lb_k = t >> 4, lb_n = (t & 15) * 4;
      *reinterpret_cast<float4*>(&Bs[lb_k][lb_n]) =
          *reinterpret_cast<const float4*>(&B[(size_t)(k0 + lb_k) * NH + bn + lb_n]);
    }
    __syncthreads();
    #pragma unroll
    for (int k = 0; k < 16; k++) {
      float2 af = *reinterpret_cast<const float2*>(&As[k][ty * 2]);
      float4 bf = *reinterpret_cast<const float4*>(&Bs[k][tx * 4]);
      acc[0][0] = fmaf(af.x, bf.x, acc[0][0]); acc[0][1] = fmaf(af.x, bf.y, acc[0][1]);
      acc[0][2] = fmaf(af.x, bf.z, acc[0][2]); acc[0][3] = fmaf(af.x, bf.w, acc[0][3]);
      acc[1][0] = fmaf(af.y, bf.x, acc[1][0]); acc[1][1] = fmaf(af.y, bf.y, acc[1][1]);
      acc[1][2] = fmaf(af.y, bf.z, acc[1][2]); acc[1][3] = fmaf(af.y, bf.w, acc[1][3]);
    }
    __syncthreads();
  }
  int cb = bn + tx * 4;
  #pragma unroll
  for (int i = 0; i < 2; i++) {
    int r = bm + ty * 2 + i;
    if (r >= M) continue;
    float4 v = make_float4(acc[i][0], acc[i][1], acc[i][2], acc[i][3]);
    *reinterpret_cast<float4*>(&C[(size_t)r * NH + cb]) = v;
  }
}

// enc1: A = [x | bnA(hagg1) | bnB(hagg2)] (K=384), bias+relu epilogue.
__global__ __launch_bounds__(256) void gemm_cat3(
    const float* __restrict__ x,
    const float* __restrict__ hagg1, const float* __restrict__ sumsA,
    const float* __restrict__ gA, const float* __restrict__ bA,
    const float* __restrict__ hagg2, const float* __restrict__ sumsB,
    const float* __restrict__ gB, const float* __restrict__ bB,
    const float* __restrict__ B, const float* __restrict__ bias,
    float* __restrict__ C, int M) {
  __shared__ __align__(16) float As[16][36];
  __shared__ __align__(16) float Bs[16][68];
  int bm = blockIdx.x * 32, bn = blockIdx.y * 64;
  int t = threadIdx.x;
  int tx = t & 15, ty = t >> 4;
  float acc[2][4];
  #pragma unroll
  for (int i = 0; i < 2; i++)
    #pragma unroll
    for (int j = 0; j < 4; j++) acc[i][j] = 0.f;

  const float invn = 1.0f / NN;
  for (int k0 = 0; k0 < 3 * NH; k0 += 16) {
    if (t < 128) {
      int la_r = t >> 2, la_k = (t & 3) * 4;
      int src = k0 >> 7;                // 0,1,2 — uniform across block
      int lc = (k0 + la_k) & (NH - 1);  // column within source
      int ar = bm + la_r;
      float4 av = make_float4(0.f, 0.f, 0.f, 0.f);
      if (ar < M) {
        if (src == 0) {
          av = *reinterpret_cast<const float4*>(&x[(size_t)ar * NH + lc]);
        } else {
          const float* hp = (src == 1) ? hagg1 : hagg2;
          const float* sp = (src == 1) ? sumsA : sumsB;
          const float* gp = (src == 1) ? gA : gB;
          const float* bp = (src == 1) ? bA : bB;
          float4 raw = *reinterpret_cast<const float4*>(&hp[(size_t)ar * NH + lc]);
          float4 sm = *reinterpret_cast<const float4*>(&sp[lc]);
          float4 sq = *reinterpret_cast<const float4*>(&sp[NH + lc]);
          float4 gv = *reinterpret_cast<const float4*>(&gp[lc]);
          float4 bv = *reinterpret_cast<const float4*>(&bp[lc]);
          float m0 = sm.x * invn, m1 = sm.y * invn, m2 = sm.z * invn, m3 = sm.w * invn;
          av.x = (raw.x - m0) * (gv.x * rsqrtf(sq.x * invn - m0 * m0 + 1e-5f)) + bv.x;
          av.y = (raw.y - m1) * (gv.y * rsqrtf(sq.y * invn - m1 * m1 + 1e-5f)) + bv.y;
          av.z = (raw.z - m2) * (gv.z * rsqrtf(sq.z * invn - m2 * m2 + 1e-5f)) + bv.z;
          av.w = (raw.w - m3) * (gv.w * rsqrtf(sq.w * invn - m3 * m3 + 1e-5f)) + bv.w;
        }
      }
      As[la_k + 0][la_r] = av.x; As[la_k + 1][la_r] = av.y;
      As[la_k + 2][la_r] = av.z; As[la_k + 3][la_r] = av.w;
    }
    {
      int lb_k = t >> 4, lb_n = (t & 15) * 4;
      *reinterpret_cast<float4*>(&Bs[lb_k][lb_n]) =
          *reinterpret_cast<const float4*>(&B[(size_t)(k0 + lb_k) * NH + bn + lb_n]);
    }
    __syncthreads();
    #pragma unroll
    for (int k = 0; k < 16; k++) {
      float2 af = *reinterpret_cast<const float2*>(&As[k][ty * 2]);
      float4 bf = *reinterpret_cast<const float4*>(&Bs[k][tx * 4]);
      acc[0][0] = fmaf(af.x, bf.x, acc[0][0]); acc[0][1] = fmaf(af.x, bf.y, acc[0][1]);
      acc[0][2] = fmaf(af.x, bf.z, acc[0][2]); acc[0][3] = fmaf(af.x, bf.w, acc[0][3]);
      acc[1][0] = fmaf(af.y, bf.x, acc[1][0]); acc[1][1] = fmaf(af.y, bf.y, acc[1][1]);
      acc[1][2] = fmaf(af.y, bf.z, acc[1][2]); acc[1][3] = fmaf(af.y, bf.w, acc[1][3]);
    }
    __syncthreads();
  }
  int cb = bn + tx * 4;
  float4 bias4 = *reinterpret_cast<const float4*>(&bias[cb]);
  #pragma unroll
  for (int i = 0; i < 2; i++) {
    int r = bm + ty * 2 + i;
    if (r >= M) continue;
    float4 v;
    v.x = fmaxf(acc[i][0] + bias4.x, 0.f);
    v.y = fmaxf(acc[i][1] + bias4.y, 0.f);
    v.z = fmaxf(acc[i][2] + bias4.z, 0.f);
    v.w = fmaxf(acc[i][3] + bias4.w, 0.f);
    *reinterpret_cast<float4*>(&C[(size_t)r * NH + cb]) = v;
  }
}

// ---------------------------------------------------------------- GCN aggregate + bias + relu
// 32 lanes per node, float4 per lane (row = 32 x 16B = 512B, fully coalesced).
__global__ void k_aggregate(const float* __restrict__ hpre, const int* __restrict__ rowptr,
                            const int* __restrict__ src, const float* __restrict__ wgt,
                            const float* __restrict__ deg, const float* __restrict__ bias,
                            float* __restrict__ outp) {
  int node = blockIdx.x * 8 + (threadIdx.x >> 5);
  int lane = threadIdx.x & 31;
  if (node >= NN) return;
  const float4* h4 = reinterpret_cast<const float4*>(hpre);
  int beg = rowptr[node], end = rowptr[node + 1];
  float4 a = make_float4(0.f, 0.f, 0.f, 0.f);
  for (int e = beg; e < end; e++) {
    int s = src[e]; float w = wgt[e];
    float4 hv = h4[(size_t)s * 32 + lane];
    a.x = fmaf(w, hv.x, a.x); a.y = fmaf(w, hv.y, a.y);
    a.z = fmaf(w, hv.z, a.z); a.w = fmaf(w, hv.w, a.w);
  }
  float d2 = 1.0f / (deg[node] + 1.0f);
  float4 hn = h4[(size_t)node * 32 + lane];
  float4 bv = reinterpret_cast<const float4*>(bias)[lane];
  float4 o;
  o.x = fmaxf(fmaf(hn.x, d2, a.x) + bv.x, 0.f);
  o.y = fmaxf(fmaf(hn.y, d2, a.y) + bv.y, 0.f);
  o.z = fmaxf(fmaf(hn.z, d2, a.z) + bv.z, 0.f);
  o.w = fmaxf(fmaf(hn.w, d2, a.w) + bv.w, 0.f);
  reinterpret_cast<float4*>(outp)[(size_t)node * 32 + lane] = o;
}

// ---------------------------------------------------------------- BN stats (raw sums)
__global__ void k_bnstats(const float* __restrict__ x, float* __restrict__ sums) {
  int f = threadIdx.x;               // 128 threads
  int rows_per = (NN + gridDim.x - 1) / gridDim.x;
  int r0 = blockIdx.x * rows_per, r1 = min(NN, r0 + rows_per);
  float s = 0.f, ss = 0.f;
  for (int r = r0; r < r1; r++) {
    float v = x[(size_t)r * NH + f];
    s += v; ss = fmaf(v, v, ss);
  }
  atomicAdd(&sums[f], s);
  atomicAdd(&sums[NH + f], ss);
}

// ---------------------------------------------------------------- cluster assign + xp0 (fused)
__global__ __launch_bounds__(128) void k_assign_xp0(
    const float* __restrict__ bottom, const float* __restrict__ mlw,
    const float* __restrict__ mlb, const float* __restrict__ gum,
    int* __restrict__ c0g, float* __restrict__ xp) {
  __shared__ float accs[C0N][NH];
  __shared__ float ws[NH * C0N];
  __shared__ int c0s[128];
  int f = threadIdx.x;
  for (int i = f; i < NH * C0N; i += 128) ws[i] = mlw[i];
  #pragma unroll
  for (int c = 0; c < C0N; c++) accs[c][f] = 0.f;
  int r0 = blockIdx.x * 128;
  int node = r0 + f;
  __syncthreads();
  if (node < NN) {
    float a[C0N];
    #pragma unroll
    for (int c = 0; c < C0N; c++) a[c] = mlb[c] + gum[node * C0N + c];
    for (int k = 0; k < NH; k += 4) {
      float4 xv = *reinterpret_cast<const float4*>(&bottom[(size_t)node * NH + k]);
      #pragma unroll
      for (int c = 0; c < C0N; c++) {
        a[c] = fmaf(xv.x, ws[(k + 0) * C0N + c], a[c]);
        a[c] = fmaf(xv.y, ws[(k + 1) * C0N + c], a[c]);
        a[c] = fmaf(xv.z, ws[(k + 2) * C0N + c], a[c]);
        a[c] = fmaf(xv.w, ws[(k + 3) * C0N + c], a[c]);
      }
    }
    int best = 0; float bv = a[0];
    #pragma unroll
    for (int c = 1; c < C0N; c++) if (a[c] > bv) { bv = a[c]; best = c; }
    c0s[f] = best; c0g[node] = best;
  }
  __syncthreads();
  int r1 = min(NN, r0 + 128);
  for (int r = r0; r < r1; r++)
    accs[c0s[r - r0]][f] += bottom[(size_t)r * NH + f];   // thread f owns column f
  #pragma unroll
  for (int c = 0; c < C0N; c++) atomicAdd(&xp[c * NH + f], accs[c][f]);
}

__global__ void k_adj2(const int* __restrict__ ei, const float* __restrict__ ew,
                       const int* __restrict__ c0, float* __restrict__ adj2) {
  __shared__ float acc[C0N * C0N];
  int t = threadIdx.x;
  if (t < C0N * C0N) acc[t] = 0.f;
  __syncthreads();
  for (int e = blockIdx.x * blockDim.x + t; e < NE; e += gridDim.x * blockDim.x) {
    int a = c0[ei[e]], b = c0[ei[NE + e]];
    atomicAdd(&acc[a * C0N + b], ew[e]);
  }
  __syncthreads();
  if (t < C0N * C0N) atomicAdd(&adj2[t], acc[t]);
}

// ---------------------------------------------------------------- both cluster levels, one block
__global__ __launch_bounds__(128) void k_level01(
    const float* __restrict__ xp_in, const float* __restrict__ adj_in,
    const float* __restrict__ me0w, const float* __restrict__ me0b,
    const float* __restrict__ ml1w, const float* __restrict__ ml1b,
    const float* __restrict__ gum1,
    const float* __restrict__ me1w, const float* __restrict__ me1b,
    float* __restrict__ lat0g, int* __restrict__ m01g, float* __restrict__ lat1g) {
  __shared__ float xp[C0N][NH];
  __shared__ float ts[C0N][NH];
  __shared__ float lat[C0N][NH];
  __shared__ float adjn[C0N * C0N];
  __shared__ float red[NH];
  __shared__ float xp1[C1N][NH];
  __shared__ float t1[C1N][NH];
  __shared__ int   m01s[C0N];
  __shared__ float a3[C1N * C1N];
  int f = threadIdx.x;
  for (int c = 0; c < C0N; c++) xp[c][f] = xp_in[c * NH + f];
  red[f] = (f < C0N * C0N) ? adj_in[f] : 0.f;
  __syncthreads();
  for (int s = 64; s > 0; s >>= 1) { if (f < s) red[f] += red[f + s]; __syncthreads(); }
  float tot = red[0];
  __syncthreads();
  if (f < C0N * C0N) adjn[f] = adj_in[f] / tot;
  for (int c = 0; c < C0N; c++) {                 // l2-normalize xp rows
    red[f] = xp[c][f] * xp[c][f];
    __syncthreads();
    for (int s = 64; s > 0; s >>= 1) { if (f < s) red[f] += red[f + s]; __syncthreads(); }
    float nrm = fmaxf(sqrtf(red[0]), 1e-12f);
    __syncthreads();
    xp[c][f] /= nrm;
  }
  __syncthreads();
  for (int i = 0; i < C0N; i++) {
    float a = 0.f;
    #pragma unroll
    for (int j = 0; j < C0N; j++) a = fmaf(adjn[i * C0N + j], xp[j][f], a);
    ts[i][f] = a;
  }
  __syncthreads();
  for (int i = 0; i < C0N; i++) {
    float a = me0b[f];
    for (int k = 0; k < NH; k++) a = fmaf(ts[i][k], me0w[k * NH + f], a);
    float l = tanhf(a);
    lat[i][f] = l;
    lat0g[i * NH + f] = l;
  }
  __syncthreads();
  // ---- level 1
  if (f < C0N) {
    float best = -1e30f; int bi = 0;
    for (int c = 0; c < C1N; c++) {
      float a = ml1b[c] + gum1[f * C1N + c];
      for (int k = 0; k < NH; k++) a = fmaf(lat[f][k], ml1w[k * C1N + c], a);
      if (a > best) { best = a; bi = c; }
    }
    m01s[f] = bi; m01g[f] = bi;
  }
  if (f < C1N * C1N) a3[f] = 0.f;
  __syncthreads();
  #pragma unroll
  for (int a = 0; a < C1N; a++) xp1[a][f] = 0.f;
  for (int i = 0; i < C0N; i++) xp1[m01s[i]][f] += lat[i][f];
  for (int c = 0; c < C1N; c++) {
    red[f] = xp1[c][f] * xp1[c][f];
    __syncthreads();
    for (int s = 64; s > 0; s >>= 1) { if (f < s) red[f] += red[f + s]; __syncthreads(); }
    float nrm = fmaxf(sqrtf(red[0]), 1e-12f);
    __syncthreads();
    xp1[c][f] /= nrm;
  }
  if (f < C0N * C0N) atomicAdd(&a3[m01s[f / C0N] * C1N + m01s[f % C0N]], adjn[f]);
  __syncthreads();
  red[f] = (f < C1N * C1N) ? a3[f] : 0.f;
  __syncthreads();
  for (int s = 64; s > 0; s >>= 1) { if (f < s) red[f] += red[f + s]; __syncthreads(); }
  float tot1 = red[0];
  __syncthreads();
  for (int i = 0; i < C1N; i++) {
    float a = 0.f;
    #pragma unroll
    for (int j = 0; j < C1N; j++) a = fmaf(a3[i * C1N + j] / tot1, xp1[j][f], a);
    t1[i][f] = a;
  }
  __syncthreads();
  for (int i = 0; i < C1N; i++) {
    float a = me1b[f];
    for (int k = 0; k < NH; k++) a = fmaf(t1[i][k], me1w[k * NH + f], a);
    lat1g[i * NH + f] = tanhf(a);
  }
}

// ---------------------------------------------------------------- fused fc1+fc2 (+ext gather)
__global__ __launch_bounds__(256) void k_fc12(
    const float* __restrict__ bottom, const int* __restrict__ c0,
    const int* __restrict__ m01, const float* __restrict__ lat0,
    const float* __restrict__ lat1,
    const float* __restrict__ w1, const float* __restrict__ b1,
    const float* __restrict__ w2, const float* __restrict__ b2,
    float* __restrict__ out) {
  __shared__ float rs[16][384];
  __shared__ float wred[16][4];
  __shared__ int cc[16], mm[16];
  int t = threadIdx.x;
  int node0 = blockIdx.x * 16;
  if (t < 16) { int c = c0[node0 + t]; cc[t] = c; mm[t] = m01[c]; }
  __syncthreads();
  for (int i = t; i < 16 * 32; i += 256) {
    int m = i >> 5, k4 = i & 31;
    ((float4*)&rs[m][0])[k4]        = ((const float4*)&bottom[(size_t)(node0 + m) * NH])[k4];
    ((float4*)&rs[m][NH])[k4]       = ((const float4*)&lat0[cc[m] * NH])[k4];
    ((float4*)&rs[m][2 * NH])[k4]   = ((const float4*)&lat1[mm[m] * NH])[k4];
  }
  __syncthreads();
  float acc0[16], acc1[16];
  #pragma unroll
  for (int m = 0; m < 16; m++) { acc0[m] = 0.f; acc1[m] = 0.f; }
  for (int k = 0; k < 384; k += 4) {
    float wa0 = w1[(size_t)(k + 0) * 512 + t], wb0 = w1[(size_t)(k + 0) * 512 + t + 256];
    float wa1 = w1[(size_t)(k + 1) * 512 + t], wb1 = w1[(size_t)(k + 1) * 512 + t + 256];
    float wa2 = w1[(size_t)(k + 2) * 512 + t], wb2 = w1[(size_t)(k + 2) * 512 + t + 256];
    float wa3 = w1[(size_t)(k + 3) * 512 + t], wb3 = w1[(size_t)(k + 3) * 512 + t + 256];
    #pragma unroll
    for (int m = 0; m < 16; m++) {
      float4 r4 = *reinterpret_cast<const float4*>(&rs[m][k]);
      acc0[m] = fmaf(r4.x, wa0, acc0[m]); acc0[m] = fmaf(r4.y, wa1, acc0[m]);
      acc0[m] = fmaf(r4.z, wa2, acc0[m]); acc0[m] = fmaf(r4.w, wa3, acc0[m]);
      acc1[m] = fmaf(r4.x, wb0, acc1[m]); acc1[m] = fmaf(r4.y, wb1, acc1[m]);
      acc1[m] = fmaf(r4.z, wb2, acc1[m]); acc1[m] = fmaf(r4.w, wb3, acc1[m]);
    }
  }
  float b1a = b1[t], b1b = b1[t + 256];
  float w2a = w2[t], w2b = w2[t + 256];
  int lane = t & 63, wid = t >> 6;
  #pragma unroll
  for (int m = 0; m < 16; m++) {
    float v = fmaxf(acc0[m] + b1a, 0.f) * w2a + fmaxf(acc1[m] + b1b, 0.f) * w2b;
    #pragma unroll
    for (int off = 32; off; off >>= 1) v += __shfl_down(v, off, 64);
    if (lane == 0) wred[m][wid] = v;
  }
  __syncthreads();
  if (t < 16) {
    float s = wred[t][0] + wred[t][1] + wred[t][2] + wred[t][3];
    out[node0 + t] = fmaxf(s + b2[0], 0.f);
  }
}

// ================================================================ launch
extern "C" void kernel_launch(void* const* d_in, const int* in_sizes, int n_in,
                              void* d_out, int out_size, void* d_ws, size_t ws_size,
                              hipStream_t stream) {
  const float* x    = (const float*)d_in[0];
  const float* ew   = (const float*)d_in[1];
  const float* gum0 = (const float*)d_in[2];
  const float* gum1 = (const float*)d_in[3];
  const float* c1w  = (const float*)d_in[4];
  const float* c1b  = (const float*)d_in[5];
  const float* c2w  = (const float*)d_in[6];
  const float* c2b  = (const float*)d_in[7];
  const float* bn1g = (const float*)d_in[8];
  const float* bn1b = (const float*)d_in[9];
  const float* bn2g = (const float*)d_in[10];
  const float* bn2b = (const float*)d_in[11];
  const float* e1w  = (const float*)d_in[12];
  const float* e1b  = (const float*)d_in[13];
  const float* e2w  = (const float*)d_in[14];
  const float* e2b  = (const float*)d_in[15];
  const float* ml0w = (const float*)d_in[16];
  const float* ml0b = (const float*)d_in[17];
  const float* ml1w = (const float*)d_in[18];
  const float* ml1b = (const float*)d_in[19];
  const float* me0w = (const float*)d_in[20];
  const float* me0b = (const float*)d_in[21];
  const float* me1w = (const float*)d_in[22];
  const float* me1b = (const float*)d_in[23];
  const float* f1w  = (const float*)d_in[24];
  const float* f1b  = (const float*)d_in[25];
  const float* f2w  = (const float*)d_in[26];
  const float* f2b  = (const float*)d_in[27];
  const int*   eidx = (const int*)d_in[28];
  float* out = (float*)d_out;

  char* p = (char*)d_ws;
  auto carve = [&](size_t bytes) -> void* {
    void* r = (void*)p; p += (bytes + 255) & ~(size_t)255; return r;
  };
  // --- zeroed group (contiguous: one memset) ---
  char*  zbase  = p;
  float* deg    = (float*)carve(NN * 4);
  int*   cnt    = (int*)carve(NN * 4);
  int*   fill   = (int*)carve(NN * 4);
  float* bnA    = (float*)carve(256 * 4);
  float* bnB    = (float*)carve(256 * 4);
  float* xp0    = (float*)carve(C0N * NH * 4);
  float* adj2   = (float*)carve(C0N * C0N * 4);
  size_t zbytes = (size_t)(p - zbase);
  // --- rest ---
  int*   rowptr = (int*)carve((NN + 1) * 4);
  int*   csrs   = (int*)carve((size_t)NE * 4);
  float* csrw   = (float*)carve((size_t)NE * 4);
  float* hpre   = (float*)carve((size_t)NN * NH * 4);
  float* hagg1  = (float*)carve((size_t)NN * NH * 4);
  float* hagg2  = (float*)carve((size_t)NN * NH * 4);
  int*   c0     = (int*)carve(NN * 4);
  float* lat0   = (float*)carve(C0N * NH * 4);
  int*   m01    = (int*)carve(C0N * 4);
  float* lat1   = (float*)carve(C1N * NH * 4);
  float* ench   = hpre;    // hpre dead after aggregate2; enc1 writes here
  float* bottom = hagg1;   // hagg1 dead after enc1 (its last reader); enc2 writes here

  hipMemsetAsync(zbase, 0, zbytes, stream);

  // graph prep interleaved with conv1's GEMM (GEMM depends only on x)
  k_deg_cnt<<<(NE + 255) / 256, 256, 0, stream>>>(eidx, ew, deg, cnt);
  k_scan<<<1, 1024, 0, stream>>>(cnt, rowptr);

  dim3 gg((NN + 31) / 32, NH / 64);   // 313 x 2 = 626 blocks
  // conv1: hpre = x @ c1w
  gemm_k<0, 0><<<gg, 256, 0, stream>>>(x, NH, c1w, NH, nullptr, hpre, NH, NN, NH);
  k_fill<<<(NE + 255) / 256, 256, 0, stream>>>(eidx, ew, deg, rowptr, fill, csrs, csrw);
  k_aggregate<<<(NN + 7) / 8, 256, 0, stream>>>(hpre, rowptr, csrs, csrw, deg, c1b, hagg1);
  k_bnstats<<<80, 128, 0, stream>>>(hagg1, bnA);
  // conv2: hpre = bnA(hagg1) @ c2w ; hagg2 = relu(agg + self + b)
  gemm_bn<<<gg, 256, 0, stream>>>(hagg1, bnA, bn1g, bn1b, c2w, hpre, NN);
  k_aggregate<<<(NN + 7) / 8, 256, 0, stream>>>(hpre, rowptr, csrs, csrw, deg, c2b, hagg2);
  k_bnstats<<<80, 128, 0, stream>>>(hagg2, bnB);
  // encoder: ench = relu([x|bnA(hagg1)|bnB(hagg2)] @ e1w + e1b); bottom = relu(ench@e2w+e2b)
  gemm_cat3<<<gg, 256, 0, stream>>>(x, hagg1, bnA, bn1g, bn1b,
                                    hagg2, bnB, bn2g, bn2b,
                                    e1w, e1b, ench, NN);
  gemm_k<1, 1><<<gg, 256, 0, stream>>>(ench, NH, e2w, NH, e2b, bottom, NH, NN, NH);
  // clustering
  k_assign_xp0<<<(NN + 127) / 128, 128, 0, stream>>>(bottom, ml0w, ml0b, gum0, c0, xp0);
  k_adj2<<<320, 256, 0, stream>>>(eidx, ew, c0, adj2);
  k_level01<<<1, 128, 0, stream>>>(xp0, adj2, me0w, me0b, ml1w, ml1b, gum1,
                                   me1w, me1b, lat0, m01, lat1);
  // head (gathers ext rows directly from lat0/lat1 via c0/m01)
  k_fc12<<<NN / 16, 256, 0, stream>>>(bottom, c0, m01, lat0, lat1,
                                      f1w, f1b, f2w, f2b, out);
}

// Round 7
// 495.118 us; speedup vs baseline: 1.0503x; 1.0503x over previous
//
#include <hip/hip_runtime.h>

#define NN 10000      // nodes
#define NE 320000     // edges
#define NH 128        // hidden
#define C0N 10
#define C1N 5

// ---------------------------------------------------------------- graph prep
__global__ void k_deg_cnt(const int* __restrict__ ei, const float* __restrict__ ew,
                          float* deg, int* cnt) {
  int e = blockIdx.x * 256 + threadIdx.x;
  if (e >= NE) return;
  int c = ei[NE + e];
  atomicAdd(&deg[c], ew[e]);
  atomicAdd(&cnt[c], 1);
}

__global__ __launch_bounds__(1024) void k_scan(const int* __restrict__ cnt, int* __restrict__ rowptr) {
  __shared__ int part[1024];
  int t = threadIdx.x;
  const int chunk = (NN + 1023) / 1024;   // 10
  int base = t * chunk;
  int s = 0;
  for (int i = 0; i < chunk; i++) { int idx = base + i; if (idx < NN) s += cnt[idx]; }
  part[t] = s; __syncthreads();
  for (int off = 1; off < 1024; off <<= 1) {
    int v = (t >= off) ? part[t - off] : 0;
    __syncthreads();
    part[t] += v;
    __syncthreads();
  }
  int run = (t == 0) ? 0 : part[t - 1];
  for (int i = 0; i < chunk; i++) { int idx = base + i; if (idx < NN) { rowptr[idx] = run; run += cnt[idx]; } }
  if (t == 1023) rowptr[NN] = run;
}

__global__ void k_fill(const int* __restrict__ ei, const float* __restrict__ ew,
                       const float* __restrict__ deg, const int* __restrict__ rowptr,
                       int* __restrict__ fill, int* __restrict__ csrs, float* __restrict__ csrw) {
  int e = blockIdx.x * 256 + threadIdx.x;
  if (e >= NE) return;
  int r = ei[e], c = ei[NE + e];
  float nrm = rsqrtf(deg[r] + 1.0f) * ew[e] * rsqrtf(deg[c] + 1.0f);
  int pos = rowptr[c] + atomicAdd(&fill[c], 1);
  csrs[pos] = r;
  csrw[pos] = nrm;
}

// ---------------------------------------------------------------- GEMM (fp32, 32x64 tile, 256 thr)
template<int BIAS, int RELU>
__global__ __launch_bounds__(256) void gemm_k(
    const float* __restrict__ A, int lda,
    const float* __restrict__ B, int ldb,
    const float* __restrict__ bias,
    float* __restrict__ C, int ldc,
    int M, int K) {
  __shared__ __align__(16) float As[16][36];
  __shared__ __align__(16) float Bs[16][68];
  int bm = blockIdx.x * 32, bn = blockIdx.y * 64;
  int t = threadIdx.x;
  int tx = t & 15, ty = t >> 4;
  float acc[2][4];
  #pragma unroll
  for (int i = 0; i < 2; i++)
    #pragma unroll
    for (int j = 0; j < 4; j++) acc[i][j] = 0.f;

  for (int k0 = 0; k0 < K; k0 += 16) {
    if (t < 128) {
      int la_r = t >> 2, la_k = (t & 3) * 4;
      int ar = bm + la_r;
      float4 av = make_float4(0.f, 0.f, 0.f, 0.f);
      if (ar < M) av = *reinterpret_cast<const float4*>(&A[(size_t)ar * lda + k0 + la_k]);
      As[la_k + 0][la_r] = av.x; As[la_k + 1][la_r] = av.y;
      As[la_k + 2][la_r] = av.z; As[la_k + 3][la_r] = av.w;
    }
    {
      int lb_k = t >> 4, lb_n = (t & 15) * 4;
      *reinterpret_cast<float4*>(&Bs[lb_k][lb_n]) =
          *reinterpret_cast<const float4*>(&B[(size_t)(k0 + lb_k) * ldb + bn + lb_n]);
    }
    __syncthreads();
    #pragma unroll
    for (int k = 0; k < 16; k++) {
      float2 af = *reinterpret_cast<const float2*>(&As[k][ty * 2]);
      float4 bf = *reinterpret_cast<const float4*>(&Bs[k][tx * 4]);
      acc[0][0] = fmaf(af.x, bf.x, acc[0][0]); acc[0][1] = fmaf(af.x, bf.y, acc[0][1]);
      acc[0][2] = fmaf(af.x, bf.z, acc[0][2]); acc[0][3] = fmaf(af.x, bf.w, acc[0][3]);
      acc[1][0] = fmaf(af.y, bf.x, acc[1][0]); acc[1][1] = fmaf(af.y, bf.y, acc[1][1]);
      acc[1][2] = fmaf(af.y, bf.z, acc[1][2]); acc[1][3] = fmaf(af.y, bf.w, acc[1][3]);
    }
    __syncthreads();
  }
  int cb = bn + tx * 4;
  float4 bias4 = make_float4(0.f, 0.f, 0.f, 0.f);
  if (BIAS) bias4 = *reinterpret_cast<const float4*>(&bias[cb]);
  #pragma unroll
  for (int i = 0; i < 2; i++) {
    int r = bm + ty * 2 + i;
    if (r >= M) continue;
    float4 v = make_float4(acc[i][0], acc[i][1], acc[i][2], acc[i][3]);
    if (BIAS) { v.x += bias4.x; v.y += bias4.y; v.z += bias4.z; v.w += bias4.w; }
    if (RELU) {
      v.x = fmaxf(v.x, 0.f); v.y = fmaxf(v.y, 0.f);
      v.z = fmaxf(v.z, 0.f); v.w = fmaxf(v.w, 0.f);
    }
    *reinterpret_cast<float4*>(&C[(size_t)r * ldc + cb]) = v;
  }
}

// C = bn(A) @ B. BN affine derived from raw sums: m=s/NN, var=ss/NN-m^2.
__global__ __launch_bounds__(256) void gemm_bn(
    const float* __restrict__ A,
    const float* __restrict__ sums,     // [256] sum | sumsq
    const float* __restrict__ g, const float* __restrict__ b,
    const float* __restrict__ B,
    float* __restrict__ C, int M) {
  __shared__ __align__(16) float As[16][36];
  __shared__ __align__(16) float Bs[16][68];
  int bm = blockIdx.x * 32, bn = blockIdx.y * 64;
  int t = threadIdx.x;
  int tx = t & 15, ty = t >> 4;
  float acc[2][4];
  #pragma unroll
  for (int i = 0; i < 2; i++)
    #pragma unroll
    for (int j = 0; j < 4; j++) acc[i][j] = 0.f;

  const float invn = 1.0f / NN;
  for (int k0 = 0; k0 < NH; k0 += 16) {
    if (t < 128) {
      int la_r = t >> 2, la_k = (t & 3) * 4;
      int ar = bm + la_r;
      int cb = k0 + la_k;
      float4 av = make_float4(0.f, 0.f, 0.f, 0.f);
      if (ar < M) {
        float4 raw = *reinterpret_cast<const float4*>(&A[(size_t)ar * NH + cb]);
        float4 sm = *reinterpret_cast<const float4*>(&sums[cb]);
        float4 sq = *reinterpret_cast<const float4*>(&sums[NH + cb]);
        float4 gv = *reinterpret_cast<const float4*>(&g[cb]);
        float4 bv = *reinterpret_cast<const float4*>(&b[cb]);
        float m0 = sm.x * invn, m1 = sm.y * invn, m2 = sm.z * invn, m3 = sm.w * invn;
        av.x = (raw.x - m0) * (gv.x * rsqrtf(sq.x * invn - m0 * m0 + 1e-5f)) + bv.x;
        av.y = (raw.y - m1) * (gv.y * rsqrtf(sq.y * invn - m1 * m1 + 1e-5f)) + bv.y;
        av.z = (raw.z - m2) * (gv.z * rsqrtf(sq.z * invn - m2 * m2 + 1e-5f)) + bv.z;
        av.w = (raw.w - m3) * (gv.w * rsqrtf(sq.w * invn - m3 * m3 + 1e-5f)) + bv.w;
      }
      As[la_k + 0][la_r] = av.x; As[la_k + 1][la_r] = av.y;
      As[la_k + 2][la_r] = av.z; As[la_k + 3][la_r] = av.w;
    }
    {
      int lb_k = t >> 4, lb_n = (t & 15) * 4;
      *reinterpret_cast<float4*>(&Bs[lb_k][lb_n]) =
          *reinterpret_cast<const float4*>(&B[(size_t)(k0 + lb_k) * NH + bn + lb_n]);
    }
    __syncthreads();
    #pragma unroll
    for (int k = 0; k < 16; k++) {
      float2 af = *reinterpret_cast<const float2*>(&As[k][ty * 2]);
      float4 bf = *reinterpret_cast<const float4*>(&Bs[k][tx * 4]);
      acc[0][0] = fmaf(af.x, bf.x, acc[0][0]); acc[0][1] = fmaf(af.x, bf.y, acc[0][1]);
      acc[0][2] = fmaf(af.x, bf.z, acc[0][2]); acc[0][3] = fmaf(af.x, bf.w, acc[0][3]);
      acc[1][0] = fmaf(af.y, bf.x, acc[1][0]); acc[1][1] = fmaf(af.y, bf.y, acc[1][1]);
      acc[1][2] = fmaf(af.y, bf.z, acc[1][2]); acc[1][3] = fmaf(af.y, bf.w, acc[1][3]);
    }
    __syncthreads();
  }
  int cb = bn + tx * 4;
  #pragma unroll
  for (int i = 0; i < 2; i++) {
    int r = bm + ty * 2 + i;
    if (r >= M) continue;
    float4 v = make_float4(acc[i][0], acc[i][1], acc[i][2], acc[i][3]);
    *reinterpret_cast<float4*>(&C[(size_t)r * NH + cb]) = v;
  }
}

// enc1: A = [x | bnA(hagg1) | bnB(hagg2)] (K=384), bias+relu epilogue.
__global__ __launch_bounds__(256) void gemm_cat3(
    const float* __restrict__ x,
    const float* __restrict__ hagg1, const float* __restrict__ sumsA,
    const float* __restrict__ gA, const float* __restrict__ bA,
    const float* __restrict__ hagg2, const float* __restrict__ sumsB,
    const float* __restrict__ gB, const float* __restrict__ bB,
    const float* __restrict__ B, const float* __restrict__ bias,
    float* __restrict__ C, int M) {
  __shared__ __align__(16) float As[16][36];
  __shared__ __align__(16) float Bs[16][68];
  int bm = blockIdx.x * 32, bn = blockIdx.y * 64;
  int t = threadIdx.x;
  int tx = t & 15, ty = t >> 4;
  float acc[2][4];
  #pragma unroll
  for (int i = 0; i < 2; i++)
    #pragma unroll
    for (int j = 0; j < 4; j++) acc[i][j] = 0.f;

  const float invn = 1.0f / NN;
  for (int k0 = 0; k0 < 3 * NH; k0 += 16) {
    if (t < 128) {
      int la_r = t >> 2, la_k = (t & 3) * 4;
      int src = k0 >> 7;
      int lc = (k0 + la_k) & (NH - 1);
      int ar = bm + la_r;
      float4 av = make_float4(0.f, 0.f, 0.f, 0.f);
      if (ar < M) {
        if (src == 0) {
          av = *reinterpret_cast<const float4*>(&x[(size_t)ar * NH + lc]);
        } else {
          const float* hp = (src == 1) ? hagg1 : hagg2;
          const float* sp = (src == 1) ? sumsA : sumsB;
          const float* gp = (src == 1) ? gA : gB;
          const float* bp = (src == 1) ? bA : bB;
          float4 raw = *reinterpret_cast<const float4*>(&hp[(size_t)ar * NH + lc]);
          float4 sm = *reinterpret_cast<const float4*>(&sp[lc]);
          float4 sq = *reinterpret_cast<const float4*>(&sp[NH + lc]);
          float4 gv = *reinterpret_cast<const float4*>(&gp[lc]);
          float4 bv = *reinterpret_cast<const float4*>(&bp[lc]);
          float m0 = sm.x * invn, m1 = sm.y * invn, m2 = sm.z * invn, m3 = sm.w * invn;
          av.x = (raw.x - m0) * (gv.x * rsqrtf(sq.x * invn - m0 * m0 + 1e-5f)) + bv.x;
          av.y = (raw.y - m1) * (gv.y * rsqrtf(sq.y * invn - m1 * m1 + 1e-5f)) + bv.y;
          av.z = (raw.z - m2) * (gv.z * rsqrtf(sq.z * invn - m2 * m2 + 1e-5f)) + bv.z;
          av.w = (raw.w - m3) * (gv.w * rsqrtf(sq.w * invn - m3 * m3 + 1e-5f)) + bv.w;
        }
      }
      As[la_k + 0][la_r] = av.x; As[la_k + 1][la_r] = av.y;
      As[la_k + 2][la_r] = av.z; As[la_k + 3][la_r] = av.w;
    }
    {
      int lb_k = t >> 4, lb_n = (t & 15) * 4;
      *reinterpret_cast<float4*>(&Bs[lb_k][lb_n]) =
          *reinterpret_cast<const float4*>(&B[(size_t)(k0 + lb_k) * NH + bn + lb_n]);
    }
    __syncthreads();
    #pragma unroll
    for (int k = 0; k < 16; k++) {
      float2 af = *reinterpret_cast<const float2*>(&As[k][ty * 2]);
      float4 bf = *reinterpret_cast<const float4*>(&Bs[k][tx * 4]);
      acc[0][0] = fmaf(af.x, bf.x, acc[0][0]); acc[0][1] = fmaf(af.x, bf.y, acc[0][1]);
      acc[0][2] = fmaf(af.x, bf.z, acc[0][2]); acc[0][3] = fmaf(af.x, bf.w, acc[0][3]);
      acc[1][0] = fmaf(af.y, bf.x, acc[1][0]); acc[1][1] = fmaf(af.y, bf.y, acc[1][1]);
      acc[1][2] = fmaf(af.y, bf.z, acc[1][2]); acc[1][3] = fmaf(af.y, bf.w, acc[1][3]);
    }
    __syncthreads();
  }
  int cb = bn + tx * 4;
  float4 bias4 = *reinterpret_cast<const float4*>(&bias[cb]);
  #pragma unroll
  for (int i = 0; i < 2; i++) {
    int r = bm + ty * 2 + i;
    if (r >= M) continue;
    float4 v;
    v.x = fmaxf(acc[i][0] + bias4.x, 0.f);
    v.y = fmaxf(acc[i][1] + bias4.y, 0.f);
    v.z = fmaxf(acc[i][2] + bias4.z, 0.f);
    v.w = fmaxf(acc[i][3] + bias4.w, 0.f);
    *reinterpret_cast<float4*>(&C[(size_t)r * NH + cb]) = v;
  }
}

// ---------------------------------------------------------------- GCN aggregate + bias + relu
// 32 lanes/node, float4/lane. Fused BN raw-sum stats (block partials -> atomicAdd).
// Grid must be exactly NN/8 blocks (NN % 8 == 0) so all threads reach barriers.
__global__ void k_aggregate(const float* __restrict__ hpre, const int* __restrict__ rowptr,
                            const int* __restrict__ src, const float* __restrict__ wgt,
                            const float* __restrict__ deg, const float* __restrict__ bias,
                            float* __restrict__ outp, float* __restrict__ sums) {
  __shared__ float bs8[8][32][4];
  __shared__ float bq8[8][32][4];
  int t = threadIdx.x;
  int grp = t >> 5, lane = t & 31;
  int node = blockIdx.x * 8 + grp;
  const float4* h4 = reinterpret_cast<const float4*>(hpre);
  int beg = rowptr[node], end = rowptr[node + 1];
  float4 a = make_float4(0.f, 0.f, 0.f, 0.f);
  for (int e = beg; e < end; e++) {
    int s = src[e]; float w = wgt[e];
    float4 hv = h4[(size_t)s * 32 + lane];
    a.x = fmaf(w, hv.x, a.x); a.y = fmaf(w, hv.y, a.y);
    a.z = fmaf(w, hv.z, a.z); a.w = fmaf(w, hv.w, a.w);
  }
  float d2 = 1.0f / (deg[node] + 1.0f);
  float4 hn = h4[(size_t)node * 32 + lane];
  float4 bv = reinterpret_cast<const float4*>(bias)[lane];
  float4 o;
  o.x = fmaxf(fmaf(hn.x, d2, a.x) + bv.x, 0.f);
  o.y = fmaxf(fmaf(hn.y, d2, a.y) + bv.y, 0.f);
  o.z = fmaxf(fmaf(hn.z, d2, a.z) + bv.z, 0.f);
  o.w = fmaxf(fmaf(hn.w, d2, a.w) + bv.w, 0.f);
  reinterpret_cast<float4*>(outp)[(size_t)node * 32 + lane] = o;
  bs8[grp][lane][0] = o.x; bs8[grp][lane][1] = o.y;
  bs8[grp][lane][2] = o.z; bs8[grp][lane][3] = o.w;
  bq8[grp][lane][0] = o.x * o.x; bq8[grp][lane][1] = o.y * o.y;
  bq8[grp][lane][2] = o.z * o.z; bq8[grp][lane][3] = o.w * o.w;
  __syncthreads();
  if (t < NH) {
    int fl = t >> 2, fj = t & 3;
    float s = 0.f, q = 0.f;
    #pragma unroll
    for (int g = 0; g < 8; g++) { s += bs8[g][fl][fj]; q += bq8[g][fl][fj]; }
    atomicAdd(&sums[t], s);
    atomicAdd(&sums[NH + t], q);
  }
}

// ---------------------------------------------------------------- cluster assign + xp0 (fused)
__global__ __launch_bounds__(128) void k_assign_xp0(
    const float* __restrict__ bottom, const float* __restrict__ mlw,
    const float* __restrict__ mlb, const float* __restrict__ gum,
    int* __restrict__ c0g, float* __restrict__ xp) {
  __shared__ float accs[C0N][NH];
  __shared__ float ws[NH * C0N];
  __shared__ int c0s[128];
  int f = threadIdx.x;
  for (int i = f; i < NH * C0N; i += 128) ws[i] = mlw[i];
  #pragma unroll
  for (int c = 0; c < C0N; c++) accs[c][f] = 0.f;
  int r0 = blockIdx.x * 128;
  int node = r0 + f;
  __syncthreads();
  if (node < NN) {
    float a[C0N];
    #pragma unroll
    for (int c = 0; c < C0N; c++) a[c] = mlb[c] + gum[node * C0N + c];
    for (int k = 0; k < NH; k += 4) {
      float4 xv = *reinterpret_cast<const float4*>(&bottom[(size_t)node * NH + k]);
      #pragma unroll
      for (int c = 0; c < C0N; c++) {
        a[c] = fmaf(xv.x, ws[(k + 0) * C0N + c], a[c]);
        a[c] = fmaf(xv.y, ws[(k + 1) * C0N + c], a[c]);
        a[c] = fmaf(xv.z, ws[(k + 2) * C0N + c], a[c]);
        a[c] = fmaf(xv.w, ws[(k + 3) * C0N + c], a[c]);
      }
    }
    int best = 0; float bv = a[0];
    #pragma unroll
    for (int c = 1; c < C0N; c++) if (a[c] > bv) { bv = a[c]; best = c; }
    c0s[f] = best; c0g[node] = best;
  }
  __syncthreads();
  int r1 = min(NN, r0 + 128);
  for (int r = r0; r < r1; r++)
    accs[c0s[r - r0]][f] += bottom[(size_t)r * NH + f];
  #pragma unroll
  for (int c = 0; c < C0N; c++) atomicAdd(&xp[c * NH + f], accs[c][f]);
}

__global__ void k_adj2(const int* __restrict__ ei, const float* __restrict__ ew,
                       const int* __restrict__ c0, float* __restrict__ adj2) {
  __shared__ float acc[C0N * C0N];
  int t = threadIdx.x;
  if (t < C0N * C0N) acc[t] = 0.f;
  __syncthreads();
  for (int e = blockIdx.x * blockDim.x + t; e < NE; e += gridDim.x * blockDim.x) {
    int a = c0[ei[e]], b = c0[ei[NE + e]];
    atomicAdd(&acc[a * C0N + b], ew[e]);
  }
  __syncthreads();
  if (t < C0N * C0N) atomicAdd(&adj2[t], acc[t]);
}

// ---------------------------------------------------------------- both cluster levels, one block
// matmuls loop-swapped: weight element loaded once (coalesced), broadcast from LDS.
__global__ __launch_bounds__(128) void k_level01(
    const float* __restrict__ xp_in, const float* __restrict__ adj_in,
    const float* __restrict__ me0w, const float* __restrict__ me0b,
    const float* __restrict__ ml1w, const float* __restrict__ ml1b,
    const float* __restrict__ gum1,
    const float* __restrict__ me1w, const float* __restrict__ me1b,
    float* __restrict__ lat0g, int* __restrict__ m01g, float* __restrict__ lat1g) {
  __shared__ float xp[C0N][NH];
  __shared__ float ts[C0N][NH];
  __shared__ float lat[C0N][NH];
  __shared__ float adjn[C0N * C0N];
  __shared__ float red[NH];
  __shared__ float xp1[C1N][NH];
  __shared__ float t1s[C1N][NH];
  __shared__ int   m01s[C0N];
  __shared__ float a3[C1N * C1N];
  int f = threadIdx.x;
  for (int c = 0; c < C0N; c++) xp[c][f] = xp_in[c * NH + f];
  red[f] = (f < C0N * C0N) ? adj_in[f] : 0.f;
  __syncthreads();
  for (int s = 64; s > 0; s >>= 1) { if (f < s) red[f] += red[f + s]; __syncthreads(); }
  float tot = red[0];
  __syncthreads();
  if (f < C0N * C0N) adjn[f] = adj_in[f] / tot;
  for (int c = 0; c < C0N; c++) {                 // l2-normalize xp rows
    red[f] = xp[c][f] * xp[c][f];
    __syncthreads();
    for (int s = 64; s > 0; s >>= 1) { if (f < s) red[f] += red[f + s]; __syncthreads(); }
    float nrm = fmaxf(sqrtf(red[0]), 1e-12f);
    __syncthreads();
    xp[c][f] /= nrm;
  }
  __syncthreads();
  for (int i = 0; i < C0N; i++) {
    float a = 0.f;
    #pragma unroll
    for (int j = 0; j < C0N; j++) a = fmaf(adjn[i * C0N + j], xp[j][f], a);
    ts[i][f] = a;
  }
  __syncthreads();
  {   // lat = tanh(ts @ me0w + me0b), loop-swapped
    float acc0[C0N];
    #pragma unroll
    for (int i = 0; i < C0N; i++) acc0[i] = 0.f;
    for (int k = 0; k < NH; k++) {
      float w = me0w[k * NH + f];
      #pragma unroll
      for (int i = 0; i < C0N; i++) acc0[i] = fmaf(ts[i][k], w, acc0[i]);
    }
    float b0 = me0b[f];
    for (int i = 0; i < C0N; i++) {
      float l = tanhf(acc0[i] + b0);
      lat[i][f] = l;
      lat0g[i * NH + f] = l;
    }
  }
  __syncthreads();
  // ---- level 1 assignment
  if (f < C0N) {
    float best = -1e30f; int bi = 0;
    for (int c = 0; c < C1N; c++) {
      float a = ml1b[c] + gum1[f * C1N + c];
      for (int k = 0; k < NH; k++) a = fmaf(lat[f][k], ml1w[k * C1N + c], a);
      if (a > best) { best = a; bi = c; }
    }
    m01s[f] = bi; m01g[f] = bi;
  }
  if (f < C1N * C1N) a3[f] = 0.f;
  __syncthreads();
  #pragma unroll
  for (int a = 0; a < C1N; a++) xp1[a][f] = 0.f;
  for (int i = 0; i < C0N; i++) xp1[m01s[i]][f] += lat[i][f];
  for (int c = 0; c < C1N; c++) {
    red[f] = xp1[c][f] * xp1[c][f];
    __syncthreads();
    for (int s = 64; s > 0; s >>= 1) { if (f < s) red[f] += red[f + s]; __syncthreads(); }
    float nrm = fmaxf(sqrtf(red[0]), 1e-12f);
    __syncthreads();
    xp1[c][f] /= nrm;
  }
  if (f < C0N * C0N) atomicAdd(&a3[m01s[f / C0N] * C1N + m01s[f % C0N]], adjn[f]);
  __syncthreads();
  red[f] = (f < C1N * C1N) ? a3[f] : 0.f;
  __syncthreads();
  for (int s = 64; s > 0; s >>= 1) { if (f < s) red[f] += red[f + s]; __syncthreads(); }
  float tot1 = red[0];
  __syncthreads();
  for (int i = 0; i < C1N; i++) {
    float a = 0.f;
    #pragma unroll
    for (int j = 0; j < C1N; j++) a = fmaf(a3[i * C1N + j] / tot1, xp1[j][f], a);
    t1s[i][f] = a;
  }
  __syncthreads();
  {   // lat1 = tanh(t1s @ me1w + me1b), loop-swapped
    float acc1[C1N];
    #pragma unroll
    for (int i = 0; i < C1N; i++) acc1[i] = 0.f;
    for (int k = 0; k < NH; k++) {
      float w = me1w[k * NH + f];
      #pragma unroll
      for (int i = 0; i < C1N; i++) acc1[i] = fmaf(t1s[i][k], w, acc1[i]);
    }
    float b1v = me1b[f];
    for (int i = 0; i < C1N; i++) lat1g[i * NH + f] = tanhf(acc1[i] + b1v);
  }
}

// ---------------------------------------------------------------- fused fc1+fc2 (+ext gather)
// 8 nodes/block, 128 threads, thread owns hidden 4t..4t+3 (contiguous float4).
// 16 FMA per ds_read_b128 -> 1 B/FMA LDS traffic; 1250 blocks.
__device__ __forceinline__ float4 fma4(float s, float4 w, float4 a) {
  a.x = fmaf(s, w.x, a.x); a.y = fmaf(s, w.y, a.y);
  a.z = fmaf(s, w.z, a.z); a.w = fmaf(s, w.w, a.w);
  return a;
}

__global__ __launch_bounds__(128) void k_fc12(
    const float* __restrict__ bottom, const int* __restrict__ c0,
    const int* __restrict__ m01, const float* __restrict__ lat0,
    const float* __restrict__ lat1,
    const float* __restrict__ w1, const float* __restrict__ b1,
    const float* __restrict__ w2, const float* __restrict__ b2,
    float* __restrict__ out) {
  __shared__ float rs[8][384];
  __shared__ float wred[8][2];
  __shared__ int cc[8], mm[8];
  int t = threadIdx.x;
  int node0 = blockIdx.x * 8;
  if (t < 8) { int c = c0[node0 + t]; cc[t] = c; mm[t] = m01[c]; }
  __syncthreads();
  for (int i = t; i < 8 * 96; i += 128) {           // 96 float4 slots per row
    int m = i / 96, k4 = i % 96;
    float4 v;
    if (k4 < 32)      v = ((const float4*)&bottom[(size_t)(node0 + m) * NH])[k4];
    else if (k4 < 64) v = ((const float4*)&lat0[cc[m] * NH])[k4 - 32];
    else              v = ((const float4*)&lat1[mm[m] * NH])[k4 - 64];
    ((float4*)&rs[m][0])[k4] = v;
  }
  __syncthreads();
  float4 acc[8];
  #pragma unroll
  for (int m = 0; m < 8; m++) acc[m] = make_float4(0.f, 0.f, 0.f, 0.f);
  int h = 4 * t;
  for (int k = 0; k < 384; k += 4) {
    float4 w0 = *(const float4*)&w1[(size_t)(k + 0) * 512 + h];
    float4 wv1 = *(const float4*)&w1[(size_t)(k + 1) * 512 + h];
    float4 wv2 = *(const float4*)&w1[(size_t)(k + 2) * 512 + h];
    float4 wv3 = *(const float4*)&w1[(size_t)(k + 3) * 512 + h];
    #pragma unroll
    for (int m = 0; m < 8; m++) {
      float4 r = *(const float4*)&rs[m][k];
      acc[m] = fma4(r.x, w0, acc[m]);
      acc[m] = fma4(r.y, wv1, acc[m]);
      acc[m] = fma4(r.z, wv2, acc[m]);
      acc[m] = fma4(r.w, wv3, acc[m]);
    }
  }
  float4 b14 = *(const float4*)&b1[h];
  float4 w24 = *(const float4*)&w2[h];
  int lane = t & 63, wid = t >> 6;
  #pragma unroll
  for (int m = 0; m < 8; m++) {
    float v = fmaxf(acc[m].x + b14.x, 0.f) * w24.x
            + fmaxf(acc[m].y + b14.y, 0.f) * w24.y
            + fmaxf(acc[m].z + b14.z, 0.f) * w24.z
            + fmaxf(acc[m].w + b14.w, 0.f) * w24.w;
    #pragma unroll
    for (int off = 32; off; off >>= 1) v += __shfl_down(v, off, 64);
    if (lane == 0) wred[m][wid] = v;
  }
  __syncthreads();
  if (t < 8) out[node0 + t] = fmaxf(wred[t][0] + wred[t][1] + b2[0], 0.f);
}

// ================================================================ launch
extern "C" void kernel_launch(void* const* d_in, const int* in_sizes, int n_in,
                              void* d_out, int out_size, void* d_ws, size_t ws_size,
                              hipStream_t stream) {
  const float* x    = (const float*)d_in[0];
  const float* ew   = (const float*)d_in[1];
  const float* gum0 = (const float*)d_in[2];
  const float* gum1 = (const float*)d_in[3];
  const float* c1w  = (const float*)d_in[4];
  const float* c1b  = (const float*)d_in[5];
  const float* c2w  = (const float*)d_in[6];
  const float* c2b  = (const float*)d_in[7];
  const float* bn1g = (const float*)d_in[8];
  const float* bn1b = (const float*)d_in[9];
  const float* bn2g = (const float*)d_in[10];
  const float* bn2b = (const float*)d_in[11];
  const float* e1w  = (const float*)d_in[12];
  const float* e1b  = (const float*)d_in[13];
  const float* e2w  = (const float*)d_in[14];
  const float* e2b  = (const float*)d_in[15];
  const float* ml0w = (const float*)d_in[16];
  const float* ml0b = (const float*)d_in[17];
  const float* ml1w = (const float*)d_in[18];
  const float* ml1b = (const float*)d_in[19];
  const float* me0w = (const float*)d_in[20];
  const float* me0b = (const float*)d_in[21];
  const float* me1w = (const float*)d_in[22];
  const float* me1b = (const float*)d_in[23];
  const float* f1w  = (const float*)d_in[24];
  const float* f1b  = (const float*)d_in[25];
  const float* f2w  = (const float*)d_in[26];
  const float* f2b  = (const float*)d_in[27];
  const int*   eidx = (const int*)d_in[28];
  float* out = (float*)d_out;

  char* p = (char*)d_ws;
  auto carve = [&](size_t bytes) -> void* {
    void* r = (void*)p; p += (bytes + 255) & ~(size_t)255; return r;
  };
  // --- zeroed group (contiguous: one memset) ---
  char*  zbase  = p;
  float* deg    = (float*)carve(NN * 4);
  int*   cnt    = (int*)carve(NN * 4);
  int*   fill   = (int*)carve(NN * 4);
  float* bnA    = (float*)carve(256 * 4);
  float* bnB    = (float*)carve(256 * 4);
  float* xp0    = (float*)carve(C0N * NH * 4);
  float* adj2   = (float*)carve(C0N * C0N * 4);
  size_t zbytes = (size_t)(p - zbase);
  // --- rest ---
  int*   rowptr = (int*)carve((NN + 1) * 4);
  int*   csrs   = (int*)carve((size_t)NE * 4);
  float* csrw   = (float*)carve((size_t)NE * 4);
  float* hpre   = (float*)carve((size_t)NN * NH * 4);
  float* hagg1  = (float*)carve((size_t)NN * NH * 4);
  float* hagg2  = (float*)carve((size_t)NN * NH * 4);
  int*   c0     = (int*)carve(NN * 4);
  float* lat0   = (float*)carve(C0N * NH * 4);
  int*   m01    = (int*)carve(C0N * 4);
  float* lat1   = (float*)carve(C1N * NH * 4);
  float* ench   = hpre;    // hpre dead after aggregate2; enc1 writes here
  float* bottom = hagg1;   // hagg1 dead after enc1 (its last reader); enc2 writes here

  hipMemsetAsync(zbase, 0, zbytes, stream);

  // graph prep interleaved with conv1's GEMM (GEMM depends only on x)
  k_deg_cnt<<<(NE + 255) / 256, 256, 0, stream>>>(eidx, ew, deg, cnt);
  k_scan<<<1, 1024, 0, stream>>>(cnt, rowptr);

  dim3 gg((NN + 31) / 32, NH / 64);   // 313 x 2 = 626 blocks
  // conv1: hpre = x @ c1w
  gemm_k<0, 0><<<gg, 256, 0, stream>>>(x, NH, c1w, NH, nullptr, hpre, NH, NN, NH);
  k_fill<<<(NE + 255) / 256, 256, 0, stream>>>(eidx, ew, deg, rowptr, fill, csrs, csrw);
  k_aggregate<<<NN / 8, 256, 0, stream>>>(hpre, rowptr, csrs, csrw, deg, c1b, hagg1, bnA);
  // conv2: hpre = bnA(hagg1) @ c2w ; hagg2 = relu(agg + self + b) (+bnB stats)
  gemm_bn<<<gg, 256, 0, stream>>>(hagg1, bnA, bn1g, bn1b, c2w, hpre, NN);
  k_aggregate<<<NN / 8, 256, 0, stream>>>(hpre, rowptr, csrs, csrw, deg, c2b, hagg2, bnB);
  // encoder
  gemm_cat3<<<gg, 256, 0, stream>>>(x, hagg1, bnA, bn1g, bn1b,
                                    hagg2, bnB, bn2g, bn2b,
                                    e1w, e1b, ench, NN);
  gemm_k<1, 1><<<gg, 256, 0, stream>>>(ench, NH, e2w, NH, e2b, bottom, NH, NN, NH);
  // clustering
  k_assign_xp0<<<(NN + 127) / 128, 128, 0, stream>>>(bottom, ml0w, ml0b, gum0, c0, xp0);
  k_adj2<<<320, 256, 0, stream>>>(eidx, ew, c0, adj2);
  k_level01<<<1, 128, 0, stream>>>(xp0, adj2, me0w, me0b, ml1w, ml1b, gum1,
                                   me1w, me1b, lat0, m01, lat1);
  // head
  k_fc12<<<NN / 8, 128, 0, stream>>>(bottom, c0, m01, lat0, lat1,
                                     f1w, f1b, f2w, f2b, out);
}

// Round 11
// 476.670 us; speedup vs baseline: 1.0909x; 1.0387x over previous
//
#include <hip/hip_runtime.h>

#define NN 10000      // nodes
#define NE 320000     // edges
#define NH 128        // hidden
#define C0N 10
#define C1N 5

// ---------------------------------------------------------------- graph prep
// deg accumulated in DOUBLE: order-invariant at fp32 level -> deterministic runs.
__global__ void k_deg_cnt(const int* __restrict__ ei, const float* __restrict__ ew,
                          double* deg, int* cnt) {
  int e = blockIdx.x * 256 + threadIdx.x;
  if (e >= NE) return;
  int c = ei[NE + e];
  atomicAdd(&deg[c], (double)ew[e]);
  atomicAdd(&cnt[c], 1);
}

__global__ __launch_bounds__(1024) void k_scan(const int* __restrict__ cnt, int* __restrict__ rowptr) {
  __shared__ int part[1024];
  int t = threadIdx.x;
  const int chunk = (NN + 1023) / 1024;   // 10
  int base = t * chunk;
  int s = 0;
  for (int i = 0; i < chunk; i++) { int idx = base + i; if (idx < NN) s += cnt[idx]; }
  part[t] = s; __syncthreads();
  for (int off = 1; off < 1024; off <<= 1) {
    int v = (t >= off) ? part[t - off] : 0;
    __syncthreads();
    part[t] += v;
    __syncthreads();
  }
  int run = (t == 0) ? 0 : part[t - 1];
  for (int i = 0; i < chunk; i++) { int idx = base + i; if (idx < NN) { rowptr[idx] = run; run += cnt[idx]; } }
  if (t == 1023) rowptr[NN] = run;
}

__global__ void k_fill(const int* __restrict__ ei, const float* __restrict__ ew,
                       const double* __restrict__ deg, const int* __restrict__ rowptr,
                       int* __restrict__ fill, int* __restrict__ csrs, float* __restrict__ csrw) {
  int e = blockIdx.x * 256 + threadIdx.x;
  if (e >= NE) return;
  int r = ei[e], c = ei[NE + e];
  float dr = (float)deg[r], dc = (float)deg[c];
  float nrm = (1.0f / sqrtf(dr + 1.0f)) * ew[e] * (1.0f / sqrtf(dc + 1.0f));
  int pos = rowptr[c] + atomicAdd(&fill[c], 1);
  csrs[pos] = r;
  csrw[pos] = nrm;
}

// ---------------------------------------------------------------- GEMM (fp32, 32x64 tile, 256 thr)
template<int BIAS, int RELU>
__global__ __launch_bounds__(256) void gemm_k(
    const float* __restrict__ A, int lda,
    const float* __restrict__ B, int ldb,
    const float* __restrict__ bias,
    float* __restrict__ C, int ldc,
    int M, int K) {
  __shared__ __align__(16) float As[16][36];
  __shared__ __align__(16) float Bs[16][68];
  int bm = blockIdx.x * 32, bn = blockIdx.y * 64;
  int t = threadIdx.x;
  int tx = t & 15, ty = t >> 4;
  float acc[2][4];
  #pragma unroll
  for (int i = 0; i < 2; i++)
    #pragma unroll
    for (int j = 0; j < 4; j++) acc[i][j] = 0.f;

  for (int k0 = 0; k0 < K; k0 += 16) {
    if (t < 128) {
      int la_r = t >> 2, la_k = (t & 3) * 4;
      int ar = bm + la_r;
      float4 av = make_float4(0.f, 0.f, 0.f, 0.f);
      if (ar < M) av = *reinterpret_cast<const float4*>(&A[(size_t)ar * lda + k0 + la_k]);
      As[la_k + 0][la_r] = av.x; As[la_k + 1][la_r] = av.y;
      As[la_k + 2][la_r] = av.z; As[la_k + 3][la_r] = av.w;
    }
    {
      int lb_k = t >> 4, lb_n = (t & 15) * 4;
      *reinterpret_cast<float4*>(&Bs[lb_k][lb_n]) =
          *reinterpret_cast<const float4*>(&B[(size_t)(k0 + lb_k) * ldb + bn + lb_n]);
    }
    __syncthreads();
    #pragma unroll
    for (int k = 0; k < 16; k++) {
      float2 af = *reinterpret_cast<const float2*>(&As[k][ty * 2]);
      float4 bf = *reinterpret_cast<const float4*>(&Bs[k][tx * 4]);
      acc[0][0] = fmaf(af.x, bf.x, acc[0][0]); acc[0][1] = fmaf(af.x, bf.y, acc[0][1]);
      acc[0][2] = fmaf(af.x, bf.z, acc[0][2]); acc[0][3] = fmaf(af.x, bf.w, acc[0][3]);
      acc[1][0] = fmaf(af.y, bf.x, acc[1][0]); acc[1][1] = fmaf(af.y, bf.y, acc[1][1]);
      acc[1][2] = fmaf(af.y, bf.z, acc[1][2]); acc[1][3] = fmaf(af.y, bf.w, acc[1][3]);
    }
    __syncthreads();
  }
  int cb = bn + tx * 4;
  float4 bias4 = make_float4(0.f, 0.f, 0.f, 0.f);
  if (BIAS) bias4 = *reinterpret_cast<const float4*>(&bias[cb]);
  #pragma unroll
  for (int i = 0; i < 2; i++) {
    int r = bm + ty * 2 + i;
    if (r >= M) continue;
    float4 v = make_float4(acc[i][0], acc[i][1], acc[i][2], acc[i][3]);
    if (BIAS) { v.x += bias4.x; v.y += bias4.y; v.z += bias4.z; v.w += bias4.w; }
    if (RELU) {
      v.x = fmaxf(v.x, 0.f); v.y = fmaxf(v.y, 0.f);
      v.z = fmaxf(v.z, 0.f); v.w = fmaxf(v.w, 0.f);
    }
    *reinterpret_cast<float4*>(&C[(size_t)r * ldc + cb]) = v;
  }
}

// BN affine from DOUBLE raw sums: m=s/NN, var=ss/NN-m^2 computed in double (no
// cancellation), then applied in fp32 like the reference.
__device__ __forceinline__ float bn_one(float raw, double s, double ss,
                                        float g, float b) {
  const double invn = 1.0 / NN;
  double md = s * invn;
  float varf = (float)(ss * invn - md * md);
  float sc = g * (1.0f / sqrtf(varf + 1e-5f));
  return (raw - (float)md) * sc + b;
}

// C = bn(A) @ B.
__global__ __launch_bounds__(256) void gemm_bn(
    const float* __restrict__ A,
    const double* __restrict__ sums,    // [256] sum | sumsq (double)
    const float* __restrict__ g, const float* __restrict__ b,
    const float* __restrict__ B,
    float* __restrict__ C, int M) {
  __shared__ __align__(16) float As[16][36];
  __shared__ __align__(16) float Bs[16][68];
  int bm = blockIdx.x * 32, bn = blockIdx.y * 64;
  int t = threadIdx.x;
  int tx = t & 15, ty = t >> 4;
  float acc[2][4];
  #pragma unroll
  for (int i = 0; i < 2; i++)
    #pragma unroll
    for (int j = 0; j < 4; j++) acc[i][j] = 0.f;

  for (int k0 = 0; k0 < NH; k0 += 16) {
    if (t < 128) {
      int la_r = t >> 2, la_k = (t & 3) * 4;
      int ar = bm + la_r;
      int cb = k0 + la_k;
      float4 av = make_float4(0.f, 0.f, 0.f, 0.f);
      if (ar < M) {
        float4 raw = *reinterpret_cast<const float4*>(&A[(size_t)ar * NH + cb]);
        float4 gv = *reinterpret_cast<const float4*>(&g[cb]);
        float4 bv = *reinterpret_cast<const float4*>(&b[cb]);
        av.x = bn_one(raw.x, sums[cb + 0], sums[NH + cb + 0], gv.x, bv.x);
        av.y = bn_one(raw.y, sums[cb + 1], sums[NH + cb + 1], gv.y, bv.y);
        av.z = bn_one(raw.z, sums[cb + 2], sums[NH + cb + 2], gv.z, bv.z);
        av.w = bn_one(raw.w, sums[cb + 3], sums[NH + cb + 3], gv.w, bv.w);
      }
      As[la_k + 0][la_r] = av.x; As[la_k + 1][la_r] = av.y;
      As[la_k + 2][la_r] = av.z; As[la_k + 3][la_r] = av.w;
    }
    {
      int lb_k = t >> 4, lb_n = (t & 15) * 4;
      *reinterpret_cast<float4*>(&Bs[lb_k][lb_n]) =
          *reinterpret_cast<const float4*>(&B[(size_t)(k0 + lb_k) * NH + bn + lb_n]);
    }
    __syncthreads();
    #pragma unroll
    for (int k = 0; k < 16; k++) {
      float2 af = *reinterpret_cast<const float2*>(&As[k][ty * 2]);
      float4 bf = *reinterpret_cast<const float4*>(&Bs[k][tx * 4]);
      acc[0][0] = fmaf(af.x, bf.x, acc[0][0]); acc[0][1] = fmaf(af.x, bf.y, acc[0][1]);
      acc[0][2] = fmaf(af.x, bf.z, acc[0][2]); acc[0][3] = fmaf(af.x, bf.w, acc[0][3]);
      acc[1][0] = fmaf(af.y, bf.x, acc[1][0]); acc[1][1] = fmaf(af.y, bf.y, acc[1][1]);
      acc[1][2] = fmaf(af.y, bf.z, acc[1][2]); acc[1][3] = fmaf(af.y, bf.w, acc[1][3]);
    }
    __syncthreads();
  }
  int cb = bn + tx * 4;
  #pragma unroll
  for (int i = 0; i < 2; i++) {
    int r = bm + ty * 2 + i;
    if (r >= M) continue;
    float4 v = make_float4(acc[i][0], acc[i][1], acc[i][2], acc[i][3]);
    *reinterpret_cast<float4*>(&C[(size_t)r * NH + cb]) = v;
  }
}

// enc1: A = [x | bnA(hagg1) | bnB(hagg2)] (K=384), bias+relu epilogue.
__global__ __launch_bounds__(256) void gemm_cat3(
    const float* __restrict__ x,
    const float* __restrict__ hagg1, const double* __restrict__ sumsA,
    const float* __restrict__ gA, const float* __restrict__ bA,
    const float* __restrict__ hagg2, const double* __restrict__ sumsB,
    const float* __restrict__ gB, const float* __restrict__ bB,
    const float* __restrict__ B, const float* __restrict__ bias,
    float* __restrict__ C, int M) {
  __shared__ __align__(16) float As[16][36];
  __shared__ __align__(16) float Bs[16][68];
  int bm = blockIdx.x * 32, bn = blockIdx.y * 64;
  int t = threadIdx.x;
  int tx = t & 15, ty = t >> 4;
  float acc[2][4];
  #pragma unroll
  for (int i = 0; i < 2; i++)
    #pragma unroll
    for (int j = 0; j < 4; j++) acc[i][j] = 0.f;

  for (int k0 = 0; k0 < 3 * NH; k0 += 16) {
    if (t < 128) {
      int la_r = t >> 2, la_k = (t & 3) * 4;
      int src = k0 >> 7;
      int lc = (k0 + la_k) & (NH - 1);
      int ar = bm + la_r;
      float4 av = make_float4(0.f, 0.f, 0.f, 0.f);
      if (ar < M) {
        if (src == 0) {
          av = *reinterpret_cast<const float4*>(&x[(size_t)ar * NH + lc]);
        } else {
          const float*  hp = (src == 1) ? hagg1 : hagg2;
          const double* sp = (src == 1) ? sumsA : sumsB;
          const float*  gp = (src == 1) ? gA : gB;
          const float*  bp = (src == 1) ? bA : bB;
          float4 raw = *reinterpret_cast<const float4*>(&hp[(size_t)ar * NH + lc]);
          float4 gv = *reinterpret_cast<const float4*>(&gp[lc]);
          float4 bv = *reinterpret_cast<const float4*>(&bp[lc]);
          av.x = bn_one(raw.x, sp[lc + 0], sp[NH + lc + 0], gv.x, bv.x);
          av.y = bn_one(raw.y, sp[lc + 1], sp[NH + lc + 1], gv.y, bv.y);
          av.z = bn_one(raw.z, sp[lc + 2], sp[NH + lc + 2], gv.z, bv.z);
          av.w = bn_one(raw.w, sp[lc + 3], sp[NH + lc + 3], gv.w, bv.w);
        }
      }
      As[la_k + 0][la_r] = av.x; As[la_k + 1][la_r] = av.y;
      As[la_k + 2][la_r] = av.z; As[la_k + 3][la_r] = av.w;
    }
    {
      int lb_k = t >> 4, lb_n = (t & 15) * 4;
      *reinterpret_cast<float4*>(&Bs[lb_k][lb_n]) =
          *reinterpret_cast<const float4*>(&B[(size_t)(k0 + lb_k) * NH + bn + lb_n]);
    }
    __syncthreads();
    #pragma unroll
    for (int k = 0; k < 16; k++) {
      float2 af = *reinterpret_cast<const float2*>(&As[k][ty * 2]);
      float4 bf = *reinterpret_cast<const float4*>(&Bs[k][tx * 4]);
      acc[0][0] = fmaf(af.x, bf.x, acc[0][0]); acc[0][1] = fmaf(af.x, bf.y, acc[0][1]);
      acc[0][2] = fmaf(af.x, bf.z, acc[0][2]); acc[0][3] = fmaf(af.x, bf.w, acc[0][3]);
      acc[1][0] = fmaf(af.y, bf.x, acc[1][0]); acc[1][1] = fmaf(af.y, bf.y, acc[1][1]);
      acc[1][2] = fmaf(af.y, bf.z, acc[1][2]); acc[1][3] = fmaf(af.y, bf.w, acc[1][3]);
    }
    __syncthreads();
  }
  int cb = bn + tx * 4;
  float4 bias4 = *reinterpret_cast<const float4*>(&bias[cb]);
  #pragma unroll
  for (int i = 0; i < 2; i++) {
    int r = bm + ty * 2 + i;
    if (r >= M) continue;
    float4 v;
    v.x = fmaxf(acc[i][0] + bias4.x, 0.f);
    v.y = fmaxf(acc[i][1] + bias4.y, 0.f);
    v.z = fmaxf(acc[i][2] + bias4.z, 0.f);
    v.w = fmaxf(acc[i][3] + bias4.w, 0.f);
    *reinterpret_cast<float4*>(&C[(size_t)r * NH + cb]) = v;
  }
}

// ---------------------------------------------------------------- GCN aggregate + bias + relu
// Neighbor accumulation in DOUBLE: CSR fill order no longer perturbs fp32 result.
// Fused BN raw-sum stats in DOUBLE (block partials -> double atomicAdd).
__global__ void k_aggregate(const float* __restrict__ hpre, const int* __restrict__ rowptr,
                            const int* __restrict__ src, const float* __restrict__ wgt,
                            const double* __restrict__ deg, const float* __restrict__ bias,
                            float* __restrict__ outp, double* __restrict__ sums) {
  __shared__ float bs8[8][32][4];
  int t = threadIdx.x;
  int grp = t >> 5, lane = t & 31;
  int node = blockIdx.x * 8 + grp;
  const float4* h4 = reinterpret_cast<const float4*>(hpre);
  int beg = rowptr[node], end = rowptr[node + 1];
  double a0 = 0.0, a1 = 0.0, a2 = 0.0, a3 = 0.0;
  for (int e = beg; e < end; e++) {
    int s = src[e]; double w = (double)wgt[e];
    float4 hv = h4[(size_t)s * 32 + lane];
    a0 += w * (double)hv.x; a1 += w * (double)hv.y;
    a2 += w * (double)hv.z; a3 += w * (double)hv.w;
  }
  float degf = (float)deg[node];
  float dinv = 1.0f / sqrtf(degf + 1.0f);
  float d2 = dinv * dinv;
  float4 hn = h4[(size_t)node * 32 + lane];
  float4 bv = reinterpret_cast<const float4*>(bias)[lane];
  float4 o;
  o.x = fmaxf((float)a0 + hn.x * d2 + bv.x, 0.f);
  o.y = fmaxf((float)a1 + hn.y * d2 + bv.y, 0.f);
  o.z = fmaxf((float)a2 + hn.z * d2 + bv.z, 0.f);
  o.w = fmaxf((float)a3 + hn.w * d2 + bv.w, 0.f);
  reinterpret_cast<float4*>(outp)[(size_t)node * 32 + lane] = o;
  bs8[grp][lane][0] = o.x; bs8[grp][lane][1] = o.y;
  bs8[grp][lane][2] = o.z; bs8[grp][lane][3] = o.w;
  __syncthreads();
  if (t < NH) {
    int fl = t >> 2, fj = t & 3;
    double s = 0.0, q = 0.0;
    #pragma unroll
    for (int g = 0; g < 8; g++) {
      double v = (double)bs8[g][fl][fj];
      s += v; q += v * v;
    }
    atomicAdd(&sums[t], s);
    atomicAdd(&sums[NH + t], q);
  }
}

// ---------------------------------------------------------------- cluster assign + xp0 (fused)
__global__ __launch_bounds__(128) void k_assign_xp0(
    const float* __restrict__ bottom, const float* __restrict__ mlw,
    const float* __restrict__ mlb, const float* __restrict__ gum,
    int* __restrict__ c0g, float* __restrict__ xp) {
  __shared__ float accs[C0N][NH];
  __shared__ float ws[NH * C0N];
  __shared__ int c0s[128];
  int f = threadIdx.x;
  for (int i = f; i < NH * C0N; i += 128) ws[i] = mlw[i];
  #pragma unroll
  for (int c = 0; c < C0N; c++) accs[c][f] = 0.f;
  int r0 = blockIdx.x * 128;
  int node = r0 + f;
  __syncthreads();
  if (node < NN) {
    float a[C0N];
    #pragma unroll
    for (int c = 0; c < C0N; c++) a[c] = mlb[c] + gum[node * C0N + c];
    for (int k = 0; k < NH; k += 4) {
      float4 xv = *reinterpret_cast<const float4*>(&bottom[(size_t)node * NH + k]);
      #pragma unroll
      for (int c = 0; c < C0N; c++) {
        a[c] = fmaf(xv.x, ws[(k + 0) * C0N + c], a[c]);
        a[c] = fmaf(xv.y, ws[(k + 1) * C0N + c], a[c]);
        a[c] = fmaf(xv.z, ws[(k + 2) * C0N + c], a[c]);
        a[c] = fmaf(xv.w, ws[(k + 3) * C0N + c], a[c]);
      }
    }
    int best = 0; float bv = a[0];
    #pragma unroll
    for (int c = 1; c < C0N; c++) if (a[c] > bv) { bv = a[c]; best = c; }
    c0s[f] = best; c0g[node] = best;
  }
  __syncthreads();
  int r1 = min(NN, r0 + 128);
  for (int r = r0; r < r1; r++)
    accs[c0s[r - r0]][f] += bottom[(size_t)r * NH + f];
  #pragma unroll
  for (int c = 0; c < C0N; c++) atomicAdd(&xp[c * NH + f], accs[c][f]);
}

__global__ void k_adj2(const int* __restrict__ ei, const float* __restrict__ ew,
                       const int* __restrict__ c0, float* __restrict__ adj2) {
  __shared__ float acc[C0N * C0N];
  int t = threadIdx.x;
  if (t < C0N * C0N) acc[t] = 0.f;
  __syncthreads();
  for (int e = blockIdx.x * blockDim.x + t; e < NE; e += gridDim.x * blockDim.x) {
    int a = c0[ei[e]], b = c0[ei[NE + e]];
    atomicAdd(&acc[a * C0N + b], ew[e]);
  }
  __syncthreads();
  if (t < C0N * C0N) atomicAdd(&adj2[t], acc[t]);
}

// ---------------------------------------------------------------- both cluster levels, one block
__global__ __launch_bounds__(128) void k_level01(
    const float* __restrict__ xp_in, const float* __restrict__ adj_in,
    const float* __restrict__ me0w, const float* __restrict__ me0b,
    const float* __restrict__ ml1w, const float* __restrict__ ml1b,
    const float* __restrict__ gum1,
    const float* __restrict__ me1w, const float* __restrict__ me1b,
    float* __restrict__ lat0g, int* __restrict__ m01g, float* __restrict__ lat1g) {
  __shared__ float xp[C0N][NH];
  __shared__ float ts[C0N][NH];
  __shared__ float lat[C0N][NH];
  __shared__ float adjn[C0N * C0N];
  __shared__ float red[NH];
  __shared__ float xp1[C1N][NH];
  __shared__ float t1s[C1N][NH];
  __shared__ int   m01s[C0N];
  __shared__ float a3[C1N * C1N];
  int f = threadIdx.x;
  for (int c = 0; c < C0N; c++) xp[c][f] = xp_in[c * NH + f];
  red[f] = (f < C0N * C0N) ? adj_in[f] : 0.f;
  __syncthreads();
  for (int s = 64; s > 0; s >>= 1) { if (f < s) red[f] += red[f + s]; __syncthreads(); }
  float tot = red[0];
  __syncthreads();
  if (f < C0N * C0N) adjn[f] = adj_in[f] / tot;
  for (int c = 0; c < C0N; c++) {                 // l2-normalize xp rows
    red[f] = xp[c][f] * xp[c][f];
    __syncthreads();
    for (int s = 64; s > 0; s >>= 1) { if (f < s) red[f] += red[f + s]; __syncthreads(); }
    float nrm = fmaxf(sqrtf(red[0]), 1e-12f);
    __syncthreads();
    xp[c][f] /= nrm;
  }
  __syncthreads();
  for (int i = 0; i < C0N; i++) {
    float a = 0.f;
    #pragma unroll
    for (int j = 0; j < C0N; j++) a = fmaf(adjn[i * C0N + j], xp[j][f], a);
    ts[i][f] = a;
  }
  __syncthreads();
  {   // lat = tanh(ts @ me0w + me0b), loop-swapped
    float acc0[C0N];
    #pragma unroll
    for (int i = 0; i < C0N; i++) acc0[i] = 0.f;
    for (int k = 0; k < NH; k++) {
      float w = me0w[k * NH + f];
      #pragma unroll
      for (int i = 0; i < C0N; i++) acc0[i] = fmaf(ts[i][k], w, acc0[i]);
    }
    float b0 = me0b[f];
    for (int i = 0; i < C0N; i++) {
      float l = tanhf(acc0[i] + b0);
      lat[i][f] = l;
      lat0g[i * NH + f] = l;
    }
  }
  __syncthreads();
  // ---- level 1 assignment
  if (f < C0N) {
    float best = -1e30f; int bi = 0;
    for (int c = 0; c < C1N; c++) {
      float a = ml1b[c] + gum1[f * C1N + c];
      for (int k = 0; k < NH; k++) a = fmaf(lat[f][k], ml1w[k * C1N + c], a);
      if (a > best) { best = a; bi = c; }
    }
    m01s[f] = bi; m01g[f] = bi;
  }
  if (f < C1N * C1N) a3[f] = 0.f;
  __syncthreads();
  #pragma unroll
  for (int a = 0; a < C1N; a++) xp1[a][f] = 0.f;
  for (int i = 0; i < C0N; i++) xp1[m01s[i]][f] += lat[i][f];
  for (int c = 0; c < C1N; c++) {
    red[f] = xp1[c][f] * xp1[c][f];
    __syncthreads();
    for (int s = 64; s > 0; s >>= 1) { if (f < s) red[f] += red[f + s]; __syncthreads(); }
    float nrm = fmaxf(sqrtf(red[0]), 1e-12f);
    __syncthreads();
    xp1[c][f] /= nrm;
  }
  if (f < C0N * C0N) atomicAdd(&a3[m01s[f / C0N] * C1N + m01s[f % C0N]], adjn[f]);
  __syncthreads();
  red[f] = (f < C1N * C1N) ? a3[f] : 0.f;
  __syncthreads();
  for (int s = 64; s > 0; s >>= 1) { if (f < s) red[f] += red[f + s]; __syncthreads(); }
  float tot1 = red[0];
  __syncthreads();
  for (int i = 0; i < C1N; i++) {
    float a = 0.f;
    #pragma unroll
    for (int j = 0; j < C1N; j++) a = fmaf(a3[i * C1N + j] / tot1, xp1[j][f], a);
    t1s[i][f] = a;
  }
  __syncthreads();
  {   // lat1 = tanh(t1s @ me1w + me1b), loop-swapped
    float acc1[C1N];
    #pragma unroll
    for (int i = 0; i < C1N; i++) acc1[i] = 0.f;
    for (int k = 0; k < NH; k++) {
      float w = me1w[k * NH + f];
      #pragma unroll
      for (int i = 0; i < C1N; i++) acc1[i] = fmaf(t1s[i][k], w, acc1[i]);
    }
    float b1v = me1b[f];
    for (int i = 0; i < C1N; i++) lat1g[i * NH + f] = tanhf(acc1[i] + b1v);
  }
}

// ---------------------------------------------------------------- fused fc1+fc2 (+ext gather)
// 8 nodes/block, 128 threads, thread owns hidden 4t..4t+3. Next-group w1 float4s
// prefetched into registers while current group's FMAs run (L2-latency hiding).
__device__ __forceinline__ float4 fma4(float s, float4 w, float4 a) {
  a.x = fmaf(s, w.x, a.x); a.y = fmaf(s, w.y, a.y);
  a.z = fmaf(s, w.z, a.z); a.w = fmaf(s, w.w, a.w);
  return a;
}

__global__ __launch_bounds__(128) void k_fc12(
    const float* __restrict__ bottom, const int* __restrict__ c0,
    const int* __restrict__ m01, const float* __restrict__ lat0,
    const float* __restrict__ lat1,
    const float* __restrict__ w1, const float* __restrict__ b1,
    const float* __restrict__ w2, const float* __restrict__ b2,
    float* __restrict__ out) {
  __shared__ float rs[8][384];
  __shared__ float wred[8][2];
  __shared__ int cc[8], mm[8];
  int t = threadIdx.x;
  int node0 = blockIdx.x * 8;
  int h = 4 * t;
  const float* wp = w1 + h;
  float4 wc0 = *(const float4*)&wp[0 * 512];
  float4 wc1 = *(const float4*)&wp[1 * 512];
  float4 wc2 = *(const float4*)&wp[2 * 512];
  float4 wc3 = *(const float4*)&wp[3 * 512];
  if (t < 8) { int c = c0[node0 + t]; cc[t] = c; mm[t] = m01[c]; }
  __syncthreads();
  for (int i = t; i < 8 * 96; i += 128) {           // 96 float4 slots per row
    int m = i / 96, k4 = i % 96;
    float4 v;
    if (k4 < 32)      v = ((const float4*)&bottom[(size_t)(node0 + m) * NH])[k4];
    else if (k4 < 64) v = ((const float4*)&lat0[cc[m] * NH])[k4 - 32];
    else              v = ((const float4*)&lat1[mm[m] * NH])[k4 - 64];
    ((float4*)&rs[m][0])[k4] = v;
  }
  __syncthreads();
  float4 acc[8];
  #pragma unroll
  for (int m = 0; m < 8; m++) acc[m] = make_float4(0.f, 0.f, 0.f, 0.f);
  for (int k = 0; k < 384; k += 4) {
    int kn = (k + 4 < 384) ? (k + 4) : 0;           // wrapped prefetch (unused on last)
    const float* wq = w1 + (size_t)kn * 512 + h;
    float4 wn0 = *(const float4*)&wq[0];
    float4 wn1 = *(const float4*)&wq[512];
    float4 wn2 = *(const float4*)&wq[1024];
    float4 wn3 = *(const float4*)&wq[1536];
    #pragma unroll
    for (int m = 0; m < 8; m++) {
      float4 r = *(const float4*)&rs[m][k];
      acc[m] = fma4(r.x, wc0, acc[m]);
      acc[m] = fma4(r.y, wc1, acc[m]);
      acc[m] = fma4(r.z, wc2, acc[m]);
      acc[m] = fma4(r.w, wc3, acc[m]);
    }
    wc0 = wn0; wc1 = wn1; wc2 = wn2; wc3 = wn3;
  }
  float4 b14 = *(const float4*)&b1[h];
  float4 w24 = *(const float4*)&w2[h];
  int lane = t & 63, wid = t >> 6;
  #pragma unroll
  for (int m = 0; m < 8; m++) {
    float v = fmaxf(acc[m].x + b14.x, 0.f) * w24.x
            + fmaxf(acc[m].y + b14.y, 0.f) * w24.y
            + fmaxf(acc[m].z + b14.z, 0.f) * w24.z
            + fmaxf(acc[m].w + b14.w, 0.f) * w24.w;
    #pragma unroll
    for (int off = 32; off; off >>= 1) v += __shfl_down(v, off, 64);
    if (lane == 0) wred[m][wid] = v;
  }
  __syncthreads();
  if (t < 8) out[node0 + t] = fmaxf(wred[t][0] + wred[t][1] + b2[0], 0.f);
}

// ================================================================ launch
extern "C" void kernel_launch(void* const* d_in, const int* in_sizes, int n_in,
                              void* d_out, int out_size, void* d_ws, size_t ws_size,
                              hipStream_t stream) {
  const float* x    = (const float*)d_in[0];
  const float* ew   = (const float*)d_in[1];
  const float* gum0 = (const float*)d_in[2];
  const float* gum1 = (const float*)d_in[3];
  const float* c1w  = (const float*)d_in[4];
  const float* c1b  = (const float*)d_in[5];
  const float* c2w  = (const float*)d_in[6];
  const float* c2b  = (const float*)d_in[7];
  const float* bn1g = (const float*)d_in[8];
  const float* bn1b = (const float*)d_in[9];
  const float* bn2g = (const float*)d_in[10];
  const float* bn2b = (const float*)d_in[11];
  const float* e1w  = (const float*)d_in[12];
  const float* e1b  = (const float*)d_in[13];
  const float* e2w  = (const float*)d_in[14];
  const float* e2b  = (const float*)d_in[15];
  const float* ml0w = (const float*)d_in[16];
  const float* ml0b = (const float*)d_in[17];
  const float* ml1w = (const float*)d_in[18];
  const float* ml1b = (const float*)d_in[19];
  const float* me0w = (const float*)d_in[20];
  const float* me0b = (const float*)d_in[21];
  const float* me1w = (const float*)d_in[22];
  const float* me1b = (const float*)d_in[23];
  const float* f1w  = (const float*)d_in[24];
  const float* f1b  = (const float*)d_in[25];
  const float* f2w  = (const float*)d_in[26];
  const float* f2b  = (const float*)d_in[27];
  const int*   eidx = (const int*)d_in[28];
  float* out = (float*)d_out;

  char* p = (char*)d_ws;
  auto carve = [&](size_t bytes) -> void* {
    void* r = (void*)p; p += (bytes + 255) & ~(size_t)255; return r;
  };
  // --- zeroed group (contiguous: one memset; 0x00 == 0.0 for double too) ---
  char*   zbase = p;
  double* deg   = (double*)carve(NN * 8);
  int*    cnt   = (int*)carve(NN * 4);
  int*    fill  = (int*)carve(NN * 4);
  double* bnA   = (double*)carve(256 * 8);
  double* bnB   = (double*)carve(256 * 8);
  float*  xp0   = (float*)carve(C0N * NH * 4);
  float*  adj2  = (float*)carve(C0N * C0N * 4);
  size_t zbytes = (size_t)(p - zbase);
  // --- rest ---
  int*   rowptr = (int*)carve((NN + 1) * 4);
  int*   csrs   = (int*)carve((size_t)NE * 4);
  float* csrw   = (float*)carve((size_t)NE * 4);
  float* hpre   = (float*)carve((size_t)NN * NH * 4);
  float* hagg1  = (float*)carve((size_t)NN * NH * 4);
  float* hagg2  = (float*)carve((size_t)NN * NH * 4);
  int*   c0     = (int*)carve(NN * 4);
  float* lat0   = (float*)carve(C0N * NH * 4);
  int*   m01    = (int*)carve(C0N * 4);
  float* lat1   = (float*)carve(C1N * NH * 4);
  float* ench   = hpre;    // hpre dead after aggregate2; enc1 writes here
  float* bottom = hagg1;   // hagg1 dead after enc1 (its last reader); enc2 writes here

  hipMemsetAsync(zbase, 0, zbytes, stream);

  // graph prep interleaved with conv1's GEMM (GEMM depends only on x)
  k_deg_cnt<<<(NE + 255) / 256, 256, 0, stream>>>(eidx, ew, deg, cnt);
  k_scan<<<1, 1024, 0, stream>>>(cnt, rowptr);

  dim3 gg((NN + 31) / 32, NH / 64);   // 313 x 2 = 626 blocks
  // conv1: hpre = x @ c1w
  gemm_k<0, 0><<<gg, 256, 0, stream>>>(x, NH, c1w, NH, nullptr, hpre, NH, NN, NH);
  k_fill<<<(NE + 255) / 256, 256, 0, stream>>>(eidx, ew, deg, rowptr, fill, csrs, csrw);
  k_aggregate<<<NN / 8, 256, 0, stream>>>(hpre, rowptr, csrs, csrw, deg, c1b, hagg1, bnA);
  // conv2: hpre = bnA(hagg1) @ c2w ; hagg2 = relu(agg + self + b) (+bnB stats)
  gemm_bn<<<gg, 256, 0, stream>>>(hagg1, bnA, bn1g, bn1b, c2w, hpre, NN);
  k_aggregate<<<NN / 8, 256, 0, stream>>>(hpre, rowptr, csrs, csrw, deg, c2b, hagg2, bnB);
  // encoder
  gemm_cat3<<<gg, 256, 0, stream>>>(x, hagg1, bnA, bn1g, bn1b,
                                    hagg2, bnB, bn2g, bn2b,
                                    e1w, e1b, ench, NN);
  gemm_k<1, 1><<<gg, 256, 0, stream>>>(ench, NH, e2w, NH, e2b, bottom, NH, NN, NH);
  // clustering
  k_assign_xp0<<<(NN + 127) / 128, 128, 0, stream>>>(bottom, ml0w, ml0b, gum0, c0, xp0);
  k_adj2<<<320, 256, 0, stream>>>(eidx, ew, c0, adj2);
  k_level01<<<1, 128, 0, stream>>>(xp0, adj2, me0w, me0b, ml1w, ml1b, gum1,
                                   me1w, me1b, lat0, m01, lat1);
  // head
  k_fc12<<<NN / 8, 128, 0, stream>>>(bottom, c0, m01, lat0, lat1,
                                     f1w, f1b, f2w, f2b, out);
}